// Round 5
// baseline (170.971 us; speedup 1.0000x reference)
//
#include <hip/hip_runtime.h>

// B=4, Sx=Sy=512, H=128, D=2H=256, fp32.
// e1 = exp2(2log2e * x@W1^T), e2 = exp2(2log2e * y@W2^T)
// tanh(s1+s2) = 1 - 2/(e1*e2+1); score = sum_h vc[h]*tanh(.)
// constant sum_h vc[h] dropped (softmax shift-invariant); -2 folded into the
// cross-wave partial reduce. P = softmax_s(score); out = P @ x.
// Quad-rcp: v1/f1+..+v4/f4 = (n12*f34+n34*f12)/(f12*f34), one rcp per 4 h.

#define NB 4
#define SEQ 512
#define HDIM 128
#define DDIM 256

static constexpr float TWO_LOG2E = 2.8853900817779268f; // 2*log2(e)
static constexpr float LOG2E     = 1.4426950408889634f;

// ---------------- Kernel A1: partial projections (unchanged) ---------------
__global__ __launch_bounds__(256) void proj_part_kernel(
    const float* __restrict__ x, const float* __restrict__ y,
    const float* __restrict__ W1, const float* __restrict__ W2,
    float* __restrict__ part)
{
    __shared__ float As[1024];      // [8 r][128 k]
    __shared__ float sPr[8192];     // [8 ks][8 r][128 h]
    const int tid = threadIdx.x;
    const int blk = blockIdx.x;           // [0,1024)
    const int kq  = blk >> 9;             // k-half
    const int gr0 = (blk & 511) * 8;      // global row base [0,4096)

    const float* in; const float* W; int srow;
    if (gr0 < 2048) { in = x; W = W1; srow = gr0; }
    else            { in = y; W = W2; srow = gr0 - 2048; }

    {
        const int r = tid >> 5, kk = tid & 31;
        *(float4*)&As[tid * 4] =
            *(const float4*)&in[(srow + r) * 256 + kq * 128 + kk * 4];
    }
    __syncthreads();

    const int hq = tid & 31;
    const int ks = tid >> 5;

    float4 acc4[8];
    #pragma unroll
    for (int r = 0; r < 8; ++r) acc4[r] = make_float4(0.f, 0.f, 0.f, 0.f);

    #pragma unroll
    for (int u = 0; u < 4; ++u) {
        const int kof = kq * 128 + ks * 16 + u * 4;
        const float4 w0 = *(const float4*)&W[(4*hq + 0) * 256 + kof];
        const float4 w1 = *(const float4*)&W[(4*hq + 1) * 256 + kof];
        const float4 w2 = *(const float4*)&W[(4*hq + 2) * 256 + kof];
        const float4 w3 = *(const float4*)&W[(4*hq + 3) * 256 + kof];
        #pragma unroll
        for (int r = 0; r < 8; ++r) {
            const float4 a = *(const float4*)&As[r * 128 + ks * 16 + u * 4];
            acc4[r].x = fmaf(a.w,w0.w, fmaf(a.z,w0.z, fmaf(a.y,w0.y, fmaf(a.x,w0.x, acc4[r].x))));
            acc4[r].y = fmaf(a.w,w1.w, fmaf(a.z,w1.z, fmaf(a.y,w1.y, fmaf(a.x,w1.x, acc4[r].y))));
            acc4[r].z = fmaf(a.w,w2.w, fmaf(a.z,w2.z, fmaf(a.y,w2.y, fmaf(a.x,w2.x, acc4[r].z))));
            acc4[r].w = fmaf(a.w,w3.w, fmaf(a.z,w3.z, fmaf(a.y,w3.y, fmaf(a.x,w3.x, acc4[r].w))));
        }
    }
    #pragma unroll
    for (int r = 0; r < 8; ++r)
        *(float4*)&sPr[ks * 1024 + r * 128 + hq * 4] = acc4[r];
    __syncthreads();
    {
        const int r = tid >> 5, h4 = (tid & 31) * 4;
        float4 s = make_float4(0.f, 0.f, 0.f, 0.f);
        #pragma unroll
        for (int k2 = 0; k2 < 8; ++k2) {
            const float4 p = *(const float4*)&sPr[k2 * 1024 + r * 128 + h4];
            s.x += p.x; s.y += p.y; s.z += p.z; s.w += p.w;
        }
        *(float4*)&part[kq * 524288 + (gr0 + r) * 128 + h4] = s;
    }
}

// ---------------- Kernel A2: combine k-halves + exp2 (unchanged) -----------
__global__ __launch_bounds__(256) void proj_combine_kernel(
    const float* __restrict__ part,
    float* __restrict__ e1, float* __restrict__ e2)
{
    const int j = blockIdx.x * 256 + threadIdx.x;   // float4 idx [0,131072)
    const float4 p0 = ((const float4*)part)[j];
    const float4 p1 = ((const float4*)part)[j + 131072];
    float4 o;
    o.x = __builtin_amdgcn_exp2f((p0.x + p1.x) * TWO_LOG2E);
    o.y = __builtin_amdgcn_exp2f((p0.y + p1.y) * TWO_LOG2E);
    o.z = __builtin_amdgcn_exp2f((p0.z + p1.z) * TWO_LOG2E);
    o.w = __builtin_amdgcn_exp2f((p0.w + p1.w) * TWO_LOG2E);
    const int gr = j >> 5;
    if (gr < 2048) ((float4*)e1)[j] = o;
    else           ((float4*)e2)[j - 65536] = o;
}

// ---------------- Kernel B: scores + softmax -> P --------------------------
// 1024 blocks x 512 thr (8 waves). Block = (b, 2 t rows) -> 4 blocks/CU.
// Wave w: t = w>>2, h-quarter = w&3 (8 quads). e2/vc in SGPRs (uniform
// addresses via readfirstlane -> s_load). e1 staged per 64-s chunk, XOR-
// swizzled (conflict-free write+read). 4 partials per (t,s) reduced in LDS
// with -2 folded. Softmax by waves 0/1; normalized P written coalesced.
__global__ void score_kernel(
    const float* __restrict__ e1g, const float* __restrict__ e2g,
    const float* __restrict__ vc,  float* __restrict__ P)
{
    __shared__ float4 sE1q[32 * 64];   // 32 KB, [hq][s^hq]
    __shared__ float  sScore[2 * 512]; // 4 KB
    __shared__ float  sPartC[8 * 64];  // 2 KB, [w][s]

    const int tid  = threadIdx.x;
    const int b    = blockIdx.x >> 8;
    const int t0   = (blockIdx.x & 255) * 2;
    const int w    = tid >> 6;
    const int lane = tid & 63;
    const int wu   = __builtin_amdgcn_readfirstlane(w);
    const int tU   = wu >> 2;          // t this wave serves
    const int qU   = wu & 3;           // h-quarter (quads qU*8 .. qU*8+7)

    // scalar operands: 8 vc quads + 8 e2 quads -> 64 SGPRs
    float4 vcs[8];
    float4 e2s[8];
    #pragma unroll
    for (int j = 0; j < 8; ++j) {
        vcs[j] = *(const float4*)&vc[(qU * 8 + j) * 4];
        e2s[j] = *(const float4*)&e2g[(b * SEQ + t0 + tU) * HDIM + (qU * 8 + j) * 4];
    }

    // prefetch e1 chunk 0
    float4 pf[4];
    #pragma unroll
    for (int j = 0; j < 4; ++j) {
        const int i = tid + j * 512;
        const int hq = i & 31, sl = i >> 5;
        pf[j] = *(const float4*)&e1g[(b * SEQ + sl) * HDIM + hq * 4];
    }

    for (int c = 0; c < 8; ++c) {
        __syncthreads();
        #pragma unroll
        for (int j = 0; j < 4; ++j) {
            const int i = tid + j * 512;
            const int hq = i & 31, sl = i >> 5;
            sE1q[hq * 64 + (sl ^ hq)] = pf[j];
        }
        if (c > 0 && tid < 128) {
            const int t = tid >> 6, s = tid & 63;
            const float r = sPartC[(t*4+0)*64 + s] + sPartC[(t*4+1)*64 + s]
                          + sPartC[(t*4+2)*64 + s] + sPartC[(t*4+3)*64 + s];
            sScore[t * 512 + (c - 1) * 64 + s] = -2.f * r;
        }
        __syncthreads();
        if (c < 7) {
            #pragma unroll
            for (int j = 0; j < 4; ++j) {
                const int i = tid + j * 512;
                const int hq = i & 31, sl = i >> 5;
                pf[j] = *(const float4*)&e1g[(b * SEQ + (c + 1) * 64 + sl) * HDIM + hq * 4];
            }
        }
        float acc = 0.f;
        #pragma unroll
        for (int j = 0; j < 8; ++j) {
            const int hq = qU * 8 + j;
            const float4 e1 = sE1q[hq * 64 + (lane ^ hq)];
            const float4 vv = vcs[j];
            const float4 e2 = e2s[j];
            const float f1 = fmaf(e1.x, e2.x, 1.f);
            const float f2 = fmaf(e1.y, e2.y, 1.f);
            const float f3 = fmaf(e1.z, e2.z, 1.f);
            const float f4 = fmaf(e1.w, e2.w, 1.f);
            const float f12 = f1 * f2, f34 = f3 * f4;
            const float n12 = fmaf(vv.x, f2, vv.y * f1);
            const float n34 = fmaf(vv.z, f4, vv.w * f3);
            const float num = fmaf(n12, f34, n34 * f12);
            acc = fmaf(num, __builtin_amdgcn_rcpf(f12 * f34), acc);
        }
        sPartC[w * 64 + lane] = acc;
    }
    __syncthreads();
    if (tid < 128) {
        const int t = tid >> 6, s = tid & 63;
        const float r = sPartC[(t*4+0)*64 + s] + sPartC[(t*4+1)*64 + s]
                      + sPartC[(t*4+2)*64 + s] + sPartC[(t*4+3)*64 + s];
        sScore[t * 512 + 7 * 64 + s] = -2.f * r;
    }
    __syncthreads();

    // softmax: wave 0 -> t0, wave 1 -> t0+1; write normalized P
    if (w < 2) {
        float v[8];
        float m = -1e30f;
        #pragma unroll
        for (int j = 0; j < 8; ++j) {
            v[j] = sScore[w * 512 + lane + j * 64];
            m = fmaxf(m, v[j]);
        }
        #pragma unroll
        for (int off = 32; off; off >>= 1) m = fmaxf(m, __shfl_xor(m, off));
        float sum = 0.f;
        #pragma unroll
        for (int j = 0; j < 8; ++j) {
            v[j] = __builtin_amdgcn_exp2f((v[j] - m) * LOG2E);
            sum += v[j];
        }
        #pragma unroll
        for (int off = 32; off; off >>= 1) sum += __shfl_xor(sum, off);
        const float inv = __builtin_amdgcn_rcpf(sum);
        float* Prow = &P[(b * SEQ + t0 + w) * SEQ];
        #pragma unroll
        for (int j = 0; j < 8; ++j)
            Prow[lane + j * 64] = v[j] * inv;
    }
}

// ---------------- Kernel C: out = P @ x ------------------------------------
// 512 blocks x 256 thr. Block = (b, 16-t tile, 64-d quarter). s chunked by
// 128: x chunk staged [128 s][64 d] (32 KB), P chunk staged transposed
// [128 s][16 t] pad 17 (8.5 KB) -> compute reads are b128 broadcasts.
// Wave = s-quarter of the chunk; lane = d. Cross-wave reduce in LDS.
__global__ __launch_bounds__(256) void pax_kernel(
    const float* __restrict__ P, const float* __restrict__ x,
    float* __restrict__ out)
{
    __shared__ float sX[128 * 64];     // 32 KB
    __shared__ float sP[128 * 17];     // 8.5 KB
    const int tid = threadIdx.x;
    const int b   = blockIdx.x >> 7;
    const int tt  = (blockIdx.x >> 2) & 31;   // 16-t tile
    const int dq  = blockIdx.x & 3;           // 64-d quarter
    const int w    = tid >> 6;
    const int lane = tid & 63;

    float acc[16];
    #pragma unroll
    for (int t = 0; t < 16; ++t) acc[t] = 0.f;

    for (int cc = 0; cc < 4; ++cc) {
        __syncthreads();
        // stage x: 128 s x 64 d
        #pragma unroll
        for (int j = 0; j < 8; ++j) {
            const int i = tid + j * 256;
            const int s = i >> 4, d4 = (i & 15) * 4;
            *(float4*)&sX[s * 64 + d4] =
                *(const float4*)&x[(b * SEQ + cc * 128 + s) * DDIM + dq * 64 + d4];
        }
        // stage P transposed: read [t][s] coalesced, write [s][t] pad 17
        #pragma unroll
        for (int j = 0; j < 2; ++j) {
            const int i = tid + j * 256;          // [0,512): 4 t x 128 s
            const int t = i >> 7, s = i & 127;
            #pragma unroll
            for (int t4 = 0; t4 < 4; ++t4)
                sP[s * 17 + t4 * 4 + t] =
                    P[(b * SEQ + tt * 16 + t4 * 4 + t) * SEQ + cc * 128 + s];
        }
        __syncthreads();
        #pragma unroll 4
        for (int si = 0; si < 32; ++si) {
            const int s = w * 32 + si;
            const float xv = sX[s * 64 + lane];
            const float4 p0 = *(const float4*)&sP[s * 17 + 0];
            const float4 p1 = *(const float4*)&sP[s * 17 + 4];
            const float4 p2 = *(const float4*)&sP[s * 17 + 8];
            const float4 p3 = *(const float4*)&sP[s * 17 + 12];
            acc[ 0] = fmaf(p0.x, xv, acc[ 0]); acc[ 1] = fmaf(p0.y, xv, acc[ 1]);
            acc[ 2] = fmaf(p0.z, xv, acc[ 2]); acc[ 3] = fmaf(p0.w, xv, acc[ 3]);
            acc[ 4] = fmaf(p1.x, xv, acc[ 4]); acc[ 5] = fmaf(p1.y, xv, acc[ 5]);
            acc[ 6] = fmaf(p1.z, xv, acc[ 6]); acc[ 7] = fmaf(p1.w, xv, acc[ 7]);
            acc[ 8] = fmaf(p2.x, xv, acc[ 8]); acc[ 9] = fmaf(p2.y, xv, acc[ 9]);
            acc[10] = fmaf(p2.z, xv, acc[10]); acc[11] = fmaf(p2.w, xv, acc[11]);
            acc[12] = fmaf(p3.x, xv, acc[12]); acc[13] = fmaf(p3.y, xv, acc[13]);
            acc[14] = fmaf(p3.z, xv, acc[14]); acc[15] = fmaf(p3.w, xv, acc[15]);
        }
    }
    __syncthreads();
    float* sRed = sX;                  // reuse: [4 w][16 t][64 d] = 16 KB
    #pragma unroll
    for (int t = 0; t < 16; ++t)
        sRed[w * 1024 + t * 64 + lane] = acc[t];
    __syncthreads();
    #pragma unroll
    for (int j = 0; j < 4; ++j) {
        const int i = tid + j * 256;   // [0,1024): 16 t x 64 d
        const int t = i >> 6, d = i & 63;
        const float r = sRed[0*1024 + t*64 + d] + sRed[1*1024 + t*64 + d]
                      + sRed[2*1024 + t*64 + d] + sRed[3*1024 + t*64 + d];
        out[(b * SEQ + tt * 16 + t) * DDIM + dq * 64 + d] = r;
    }
}

extern "C" void kernel_launch(void* const* d_in, const int* in_sizes, int n_in,
                              void* d_out, int out_size, void* d_ws, size_t ws_size,
                              hipStream_t stream) {
    const float* x   = (const float*)d_in[0];   // (4,512,256)
    const float* y   = (const float*)d_in[1];   // (4,512,256)
    const float* W1  = (const float*)d_in[2];   // (128,256)
    const float* W2  = (const float*)d_in[3];   // (128,256)
    const float* vc  = (const float*)d_in[4];   // (1,128)
    float* outp = (float*)d_out;                // (4,512,256)

    float* ws   = (float*)d_ws;
    float* e1   = ws;                           // 1 MB
    float* e2   = ws + NB * SEQ * HDIM;         // 1 MB
    float* part = ws + 2 * NB * SEQ * HDIM;     // 4 MB
    float* P    = ws + 2 * NB * SEQ * HDIM + 2 * 4096 * HDIM;  // 4 MB

    hipLaunchKernelGGL(proj_part_kernel,    dim3(1024), dim3(256), 0, stream,
                       x, y, W1, W2, part);
    hipLaunchKernelGGL(proj_combine_kernel, dim3(512),  dim3(256), 0, stream,
                       part, e1, e2);
    hipLaunchKernelGGL(score_kernel,        dim3(1024), dim3(512), 0, stream,
                       e1, e2, vc, P);
    hipLaunchKernelGGL(pax_kernel,          dim3(512),  dim3(256), 0, stream,
                       P, x, outp);
}

// Round 6
// 170.915 us; speedup vs baseline: 1.0003x; 1.0003x over previous
//
#include <hip/hip_runtime.h>

// B=4, Sx=Sy=512, H=128, D=2H=256, fp32.
// e1 = exp2(2log2e * x@W1^T), e2 = exp2(2log2e * y@W2^T)
// tanh(s1+s2) = 1 - 2/(e1*e2+1); score = sum_h vc[h]*tanh(.)
// constant sum_h vc[h] dropped (softmax shift-invariant); -2 folded into the
// cross-wave partial reduce. P = softmax_s(score); out = P @ x.
// Quad-rcp: v1/f1+..+v4/f4 = (n12*f34+n34*f12)/(f12*f34), one rcp per 4 h.

#define NB 4
#define SEQ 512
#define HDIM 128
#define DDIM 256

static constexpr float TWO_LOG2E = 2.8853900817779268f; // 2*log2(e)
static constexpr float LOG2E     = 1.4426950408889634f;

// ---------------- Kernel A1: partial projections (unchanged) ---------------
__global__ __launch_bounds__(256) void proj_part_kernel(
    const float* __restrict__ x, const float* __restrict__ y,
    const float* __restrict__ W1, const float* __restrict__ W2,
    float* __restrict__ part)
{
    __shared__ float As[1024];      // [8 r][128 k]
    __shared__ float sPr[8192];     // [8 ks][8 r][128 h]
    const int tid = threadIdx.x;
    const int blk = blockIdx.x;           // [0,1024)
    const int kq  = blk >> 9;             // k-half
    const int gr0 = (blk & 511) * 8;      // global row base [0,4096)

    const float* in; const float* W; int srow;
    if (gr0 < 2048) { in = x; W = W1; srow = gr0; }
    else            { in = y; W = W2; srow = gr0 - 2048; }

    {
        const int r = tid >> 5, kk = tid & 31;
        *(float4*)&As[tid * 4] =
            *(const float4*)&in[(srow + r) * 256 + kq * 128 + kk * 4];
    }
    __syncthreads();

    const int hq = tid & 31;
    const int ks = tid >> 5;

    float4 acc4[8];
    #pragma unroll
    for (int r = 0; r < 8; ++r) acc4[r] = make_float4(0.f, 0.f, 0.f, 0.f);

    #pragma unroll
    for (int u = 0; u < 4; ++u) {
        const int kof = kq * 128 + ks * 16 + u * 4;
        const float4 w0 = *(const float4*)&W[(4*hq + 0) * 256 + kof];
        const float4 w1 = *(const float4*)&W[(4*hq + 1) * 256 + kof];
        const float4 w2 = *(const float4*)&W[(4*hq + 2) * 256 + kof];
        const float4 w3 = *(const float4*)&W[(4*hq + 3) * 256 + kof];
        #pragma unroll
        for (int r = 0; r < 8; ++r) {
            const float4 a = *(const float4*)&As[r * 128 + ks * 16 + u * 4];
            acc4[r].x = fmaf(a.w,w0.w, fmaf(a.z,w0.z, fmaf(a.y,w0.y, fmaf(a.x,w0.x, acc4[r].x))));
            acc4[r].y = fmaf(a.w,w1.w, fmaf(a.z,w1.z, fmaf(a.y,w1.y, fmaf(a.x,w1.x, acc4[r].y))));
            acc4[r].z = fmaf(a.w,w2.w, fmaf(a.z,w2.z, fmaf(a.y,w2.y, fmaf(a.x,w2.x, acc4[r].z))));
            acc4[r].w = fmaf(a.w,w3.w, fmaf(a.z,w3.z, fmaf(a.y,w3.y, fmaf(a.x,w3.x, acc4[r].w))));
        }
    }
    #pragma unroll
    for (int r = 0; r < 8; ++r)
        *(float4*)&sPr[ks * 1024 + r * 128 + hq * 4] = acc4[r];
    __syncthreads();
    {
        const int r = tid >> 5, h4 = (tid & 31) * 4;
        float4 s = make_float4(0.f, 0.f, 0.f, 0.f);
        #pragma unroll
        for (int k2 = 0; k2 < 8; ++k2) {
            const float4 p = *(const float4*)&sPr[k2 * 1024 + r * 128 + h4];
            s.x += p.x; s.y += p.y; s.z += p.z; s.w += p.w;
        }
        *(float4*)&part[kq * 524288 + (gr0 + r) * 128 + h4] = s;
    }
}

// ---------------- Kernel A2: combine k-halves + exp2 (unchanged) -----------
__global__ __launch_bounds__(256) void proj_combine_kernel(
    const float* __restrict__ part,
    float* __restrict__ e1, float* __restrict__ e2)
{
    const int j = blockIdx.x * 256 + threadIdx.x;   // float4 idx [0,131072)
    const float4 p0 = ((const float4*)part)[j];
    const float4 p1 = ((const float4*)part)[j + 131072];
    float4 o;
    o.x = __builtin_amdgcn_exp2f((p0.x + p1.x) * TWO_LOG2E);
    o.y = __builtin_amdgcn_exp2f((p0.y + p1.y) * TWO_LOG2E);
    o.z = __builtin_amdgcn_exp2f((p0.z + p1.z) * TWO_LOG2E);
    o.w = __builtin_amdgcn_exp2f((p0.w + p1.w) * TWO_LOG2E);
    const int gr = j >> 5;
    if (gr < 2048) ((float4*)e1)[j] = o;
    else           ((float4*)e2)[j - 65536] = o;
}

// ---------------- Kernel B: scores + softmax -> P --------------------------
// 1024 blocks x 512 thr (8 waves). Block = (b, 2 t rows) -> 4 blocks/CU.
// Wave w: t = w>>2, h-quarter = w&3 (8 quads). e2/vc in SGPRs (uniform
// addresses via readfirstlane -> s_load). e1 staged per 64-s chunk, XOR-
// swizzled (conflict-free write+read). 4 partials per (t,s) reduced in LDS
// with -2 folded. Softmax by waves 0/1; normalized P written coalesced.
// __launch_bounds__(512) is LOAD-BEARING: without it the compiler clamps to
// 32 VGPRs and spills the pf[] prefetch to scratch (R5: 200 MB WRITE_SIZE).
__global__ __launch_bounds__(512) void score_kernel(
    const float* __restrict__ e1g, const float* __restrict__ e2g,
    const float* __restrict__ vc,  float* __restrict__ P)
{
    __shared__ float4 sE1q[32 * 64];   // 32 KB, [hq][s^hq]
    __shared__ float  sScore[2 * 512]; // 4 KB
    __shared__ float  sPartC[8 * 64];  // 2 KB, [w][s]

    const int tid  = threadIdx.x;
    const int b    = blockIdx.x >> 8;
    const int t0   = (blockIdx.x & 255) * 2;
    const int w    = tid >> 6;
    const int lane = tid & 63;
    const int wu   = __builtin_amdgcn_readfirstlane(w);
    const int tU   = wu >> 2;          // t this wave serves
    const int qU   = wu & 3;           // h-quarter (quads qU*8 .. qU*8+7)

    // scalar operands: 8 vc quads + 8 e2 quads -> 64 SGPRs
    float4 vcs[8];
    float4 e2s[8];
    #pragma unroll
    for (int j = 0; j < 8; ++j) {
        vcs[j] = *(const float4*)&vc[(qU * 8 + j) * 4];
        e2s[j] = *(const float4*)&e2g[(b * SEQ + t0 + tU) * HDIM + (qU * 8 + j) * 4];
    }

    // prefetch e1 chunk 0
    float4 pf[4];
    #pragma unroll
    for (int j = 0; j < 4; ++j) {
        const int i = tid + j * 512;
        const int hq = i & 31, sl = i >> 5;
        pf[j] = *(const float4*)&e1g[(b * SEQ + sl) * HDIM + hq * 4];
    }

    for (int c = 0; c < 8; ++c) {
        __syncthreads();
        #pragma unroll
        for (int j = 0; j < 4; ++j) {
            const int i = tid + j * 512;
            const int hq = i & 31, sl = i >> 5;
            sE1q[hq * 64 + (sl ^ hq)] = pf[j];
        }
        if (c > 0 && tid < 128) {
            const int t = tid >> 6, s = tid & 63;
            const float r = sPartC[(t*4+0)*64 + s] + sPartC[(t*4+1)*64 + s]
                          + sPartC[(t*4+2)*64 + s] + sPartC[(t*4+3)*64 + s];
            sScore[t * 512 + (c - 1) * 64 + s] = -2.f * r;
        }
        __syncthreads();
        if (c < 7) {
            #pragma unroll
            for (int j = 0; j < 4; ++j) {
                const int i = tid + j * 512;
                const int hq = i & 31, sl = i >> 5;
                pf[j] = *(const float4*)&e1g[(b * SEQ + (c + 1) * 64 + sl) * HDIM + hq * 4];
            }
        }
        float acc = 0.f;
        #pragma unroll
        for (int j = 0; j < 8; ++j) {
            const int hq = qU * 8 + j;
            const float4 e1 = sE1q[hq * 64 + (lane ^ hq)];
            const float4 vv = vcs[j];
            const float4 e2 = e2s[j];
            const float f1 = fmaf(e1.x, e2.x, 1.f);
            const float f2 = fmaf(e1.y, e2.y, 1.f);
            const float f3 = fmaf(e1.z, e2.z, 1.f);
            const float f4 = fmaf(e1.w, e2.w, 1.f);
            const float f12 = f1 * f2, f34 = f3 * f4;
            const float n12 = fmaf(vv.x, f2, vv.y * f1);
            const float n34 = fmaf(vv.z, f4, vv.w * f3);
            const float num = fmaf(n12, f34, n34 * f12);
            acc = fmaf(num, __builtin_amdgcn_rcpf(f12 * f34), acc);
        }
        sPartC[w * 64 + lane] = acc;
    }
    __syncthreads();
    if (tid < 128) {
        const int t = tid >> 6, s = tid & 63;
        const float r = sPartC[(t*4+0)*64 + s] + sPartC[(t*4+1)*64 + s]
                      + sPartC[(t*4+2)*64 + s] + sPartC[(t*4+3)*64 + s];
        sScore[t * 512 + 7 * 64 + s] = -2.f * r;
    }
    __syncthreads();

    // softmax: wave 0 -> t0, wave 1 -> t0+1; write normalized P
    if (w < 2) {
        float v[8];
        float m = -1e30f;
        #pragma unroll
        for (int j = 0; j < 8; ++j) {
            v[j] = sScore[w * 512 + lane + j * 64];
            m = fmaxf(m, v[j]);
        }
        #pragma unroll
        for (int off = 32; off; off >>= 1) m = fmaxf(m, __shfl_xor(m, off));
        float sum = 0.f;
        #pragma unroll
        for (int j = 0; j < 8; ++j) {
            v[j] = __builtin_amdgcn_exp2f((v[j] - m) * LOG2E);
            sum += v[j];
        }
        #pragma unroll
        for (int off = 32; off; off >>= 1) sum += __shfl_xor(sum, off);
        const float inv = __builtin_amdgcn_rcpf(sum);
        float* Prow = &P[(b * SEQ + t0 + w) * SEQ];
        #pragma unroll
        for (int j = 0; j < 8; ++j)
            Prow[lane + j * 64] = v[j] * inv;
    }
}

// ---------------- Kernel C: out = P @ x ------------------------------------
// 512 blocks x 256 thr. Block = (b, 16-t tile, 64-d quarter). s chunked by
// 128: x chunk staged [128 s][64 d] (32 KB), P chunk staged transposed
// [128 s][16 t] pad 17 (8.5 KB) -> compute reads are b128 broadcasts.
// Wave = s-quarter of the chunk; lane = d. Cross-wave reduce in LDS.
__global__ __launch_bounds__(256) void pax_kernel(
    const float* __restrict__ P, const float* __restrict__ x,
    float* __restrict__ out)
{
    __shared__ float sX[128 * 64];     // 32 KB
    __shared__ float sP[128 * 17];     // 8.5 KB
    const int tid = threadIdx.x;
    const int b   = blockIdx.x >> 7;
    const int tt  = (blockIdx.x >> 2) & 31;   // 16-t tile
    const int dq  = blockIdx.x & 3;           // 64-d quarter
    const int w    = tid >> 6;
    const int lane = tid & 63;

    float acc[16];
    #pragma unroll
    for (int t = 0; t < 16; ++t) acc[t] = 0.f;

    for (int cc = 0; cc < 4; ++cc) {
        __syncthreads();
        // stage x: 128 s x 64 d
        #pragma unroll
        for (int j = 0; j < 8; ++j) {
            const int i = tid + j * 256;
            const int s = i >> 4, d4 = (i & 15) * 4;
            *(float4*)&sX[s * 64 + d4] =
                *(const float4*)&x[(b * SEQ + cc * 128 + s) * DDIM + dq * 64 + d4];
        }
        // stage P transposed: read [t][s] coalesced, write [s][t] pad 17
        #pragma unroll
        for (int j = 0; j < 2; ++j) {
            const int i = tid + j * 256;          // [0,512): 4 t x 128 s
            const int t = i >> 7, s = i & 127;
            #pragma unroll
            for (int t4 = 0; t4 < 4; ++t4)
                sP[s * 17 + t4 * 4 + t] =
                    P[(b * SEQ + tt * 16 + t4 * 4 + t) * SEQ + cc * 128 + s];
        }
        __syncthreads();
        #pragma unroll 4
        for (int si = 0; si < 32; ++si) {
            const int s = w * 32 + si;
            const float xv = sX[s * 64 + lane];
            const float4 p0 = *(const float4*)&sP[s * 17 + 0];
            const float4 p1 = *(const float4*)&sP[s * 17 + 4];
            const float4 p2 = *(const float4*)&sP[s * 17 + 8];
            const float4 p3 = *(const float4*)&sP[s * 17 + 12];
            acc[ 0] = fmaf(p0.x, xv, acc[ 0]); acc[ 1] = fmaf(p0.y, xv, acc[ 1]);
            acc[ 2] = fmaf(p0.z, xv, acc[ 2]); acc[ 3] = fmaf(p0.w, xv, acc[ 3]);
            acc[ 4] = fmaf(p1.x, xv, acc[ 4]); acc[ 5] = fmaf(p1.y, xv, acc[ 5]);
            acc[ 6] = fmaf(p1.z, xv, acc[ 6]); acc[ 7] = fmaf(p1.w, xv, acc[ 7]);
            acc[ 8] = fmaf(p2.x, xv, acc[ 8]); acc[ 9] = fmaf(p2.y, xv, acc[ 9]);
            acc[10] = fmaf(p2.z, xv, acc[10]); acc[11] = fmaf(p2.w, xv, acc[11]);
            acc[12] = fmaf(p3.x, xv, acc[12]); acc[13] = fmaf(p3.y, xv, acc[13]);
            acc[14] = fmaf(p3.z, xv, acc[14]); acc[15] = fmaf(p3.w, xv, acc[15]);
        }
    }
    __syncthreads();
    float* sRed = sX;                  // reuse: [4 w][16 t][64 d] = 16 KB
    #pragma unroll
    for (int t = 0; t < 16; ++t)
        sRed[w * 1024 + t * 64 + lane] = acc[t];
    __syncthreads();
    #pragma unroll
    for (int j = 0; j < 4; ++j) {
        const int i = tid + j * 256;   // [0,1024): 16 t x 64 d
        const int t = i >> 6, d = i & 63;
        const float r = sRed[0*1024 + t*64 + d] + sRed[1*1024 + t*64 + d]
                      + sRed[2*1024 + t*64 + d] + sRed[3*1024 + t*64 + d];
        out[(b * SEQ + tt * 16 + t) * DDIM + dq * 64 + d] = r;
    }
}

extern "C" void kernel_launch(void* const* d_in, const int* in_sizes, int n_in,
                              void* d_out, int out_size, void* d_ws, size_t ws_size,
                              hipStream_t stream) {
    const float* x   = (const float*)d_in[0];   // (4,512,256)
    const float* y   = (const float*)d_in[1];   // (4,512,256)
    const float* W1  = (const float*)d_in[2];   // (128,256)
    const float* W2  = (const float*)d_in[3];   // (128,256)
    const float* vc  = (const float*)d_in[4];   // (1,128)
    float* outp = (float*)d_out;                // (4,512,256)

    float* ws   = (float*)d_ws;
    float* e1   = ws;                           // 1 MB
    float* e2   = ws + NB * SEQ * HDIM;         // 1 MB
    float* part = ws + 2 * NB * SEQ * HDIM;     // 4 MB
    float* P    = ws + 2 * NB * SEQ * HDIM + 2 * 4096 * HDIM;  // 4 MB

    hipLaunchKernelGGL(proj_part_kernel,    dim3(1024), dim3(256), 0, stream,
                       x, y, W1, W2, part);
    hipLaunchKernelGGL(proj_combine_kernel, dim3(512),  dim3(256), 0, stream,
                       part, e1, e2);
    hipLaunchKernelGGL(score_kernel,        dim3(1024), dim3(512), 0, stream,
                       e1, e2, vc, P);
    hipLaunchKernelGGL(pax_kernel,          dim3(512),  dim3(256), 0, stream,
                       P, x, outp);
}

// Round 7
// 170.545 us; speedup vs baseline: 1.0025x; 1.0022x over previous
//
#include <hip/hip_runtime.h>

// B=4, Sx=Sy=512, H=128, D=2H=256, fp32.
// e1 = exp2(2log2e * x@W1^T), e2 = exp2(2log2e * y@W2^T)
// tanh(s1+s2) = 1 - 2/(e1*e2+1); score = sum_h vc[h]*tanh(.)
// constant sum_h vc[h] dropped (softmax shift-invariant); -2 folded into the
// cross-wave partial reduce. P = softmax_s(score); out = P @ x.
// Quad-rcp: v1/f1+..+v4/f4 = (n12*f34+n34*f12)/(f12*f34), one rcp per 4 h.

#define NB 4
#define SEQ 512
#define HDIM 128
#define DDIM 256

static constexpr float TWO_LOG2E = 2.8853900817779268f; // 2*log2(e)
static constexpr float LOG2E     = 1.4426950408889634f;

// ---------------- Kernel A1: partial projections (unchanged) ---------------
__global__ __launch_bounds__(256) void proj_part_kernel(
    const float* __restrict__ x, const float* __restrict__ y,
    const float* __restrict__ W1, const float* __restrict__ W2,
    float* __restrict__ part)
{
    __shared__ float As[1024];      // [8 r][128 k]
    __shared__ float sPr[8192];     // [8 ks][8 r][128 h]
    const int tid = threadIdx.x;
    const int blk = blockIdx.x;           // [0,1024)
    const int kq  = blk >> 9;             // k-half
    const int gr0 = (blk & 511) * 8;      // global row base [0,4096)

    const float* in; const float* W; int srow;
    if (gr0 < 2048) { in = x; W = W1; srow = gr0; }
    else            { in = y; W = W2; srow = gr0 - 2048; }

    {
        const int r = tid >> 5, kk = tid & 31;
        *(float4*)&As[tid * 4] =
            *(const float4*)&in[(srow + r) * 256 + kq * 128 + kk * 4];
    }
    __syncthreads();

    const int hq = tid & 31;
    const int ks = tid >> 5;

    float4 acc4[8];
    #pragma unroll
    for (int r = 0; r < 8; ++r) acc4[r] = make_float4(0.f, 0.f, 0.f, 0.f);

    #pragma unroll
    for (int u = 0; u < 4; ++u) {
        const int kof = kq * 128 + ks * 16 + u * 4;
        const float4 w0 = *(const float4*)&W[(4*hq + 0) * 256 + kof];
        const float4 w1 = *(const float4*)&W[(4*hq + 1) * 256 + kof];
        const float4 w2 = *(const float4*)&W[(4*hq + 2) * 256 + kof];
        const float4 w3 = *(const float4*)&W[(4*hq + 3) * 256 + kof];
        #pragma unroll
        for (int r = 0; r < 8; ++r) {
            const float4 a = *(const float4*)&As[r * 128 + ks * 16 + u * 4];
            acc4[r].x = fmaf(a.w,w0.w, fmaf(a.z,w0.z, fmaf(a.y,w0.y, fmaf(a.x,w0.x, acc4[r].x))));
            acc4[r].y = fmaf(a.w,w1.w, fmaf(a.z,w1.z, fmaf(a.y,w1.y, fmaf(a.x,w1.x, acc4[r].y))));
            acc4[r].z = fmaf(a.w,w2.w, fmaf(a.z,w2.z, fmaf(a.y,w2.y, fmaf(a.x,w2.x, acc4[r].z))));
            acc4[r].w = fmaf(a.w,w3.w, fmaf(a.z,w3.z, fmaf(a.y,w3.y, fmaf(a.x,w3.x, acc4[r].w))));
        }
    }
    #pragma unroll
    for (int r = 0; r < 8; ++r)
        *(float4*)&sPr[ks * 1024 + r * 128 + hq * 4] = acc4[r];
    __syncthreads();
    {
        const int r = tid >> 5, h4 = (tid & 31) * 4;
        float4 s = make_float4(0.f, 0.f, 0.f, 0.f);
        #pragma unroll
        for (int k2 = 0; k2 < 8; ++k2) {
            const float4 p = *(const float4*)&sPr[k2 * 1024 + r * 128 + h4];
            s.x += p.x; s.y += p.y; s.z += p.z; s.w += p.w;
        }
        *(float4*)&part[kq * 524288 + (gr0 + r) * 128 + h4] = s;
    }
}

// ---------------- Kernel A2: combine k-halves + exp2 (unchanged) -----------
__global__ __launch_bounds__(256) void proj_combine_kernel(
    const float* __restrict__ part,
    float* __restrict__ e1, float* __restrict__ e2)
{
    const int j = blockIdx.x * 256 + threadIdx.x;   // float4 idx [0,131072)
    const float4 p0 = ((const float4*)part)[j];
    const float4 p1 = ((const float4*)part)[j + 131072];
    float4 o;
    o.x = __builtin_amdgcn_exp2f((p0.x + p1.x) * TWO_LOG2E);
    o.y = __builtin_amdgcn_exp2f((p0.y + p1.y) * TWO_LOG2E);
    o.z = __builtin_amdgcn_exp2f((p0.z + p1.z) * TWO_LOG2E);
    o.w = __builtin_amdgcn_exp2f((p0.w + p1.w) * TWO_LOG2E);
    const int gr = j >> 5;
    if (gr < 2048) ((float4*)e1)[j] = o;
    else           ((float4*)e2)[j - 65536] = o;
}

// ---------------- Kernel B: scores + softmax -> P --------------------------
// 1024 blocks x 512 thr (8 waves). Block = (b, 2 t rows). Wave w: t = w>>2,
// h-quarter = w&3 (8 quads). e2/vc in SGPRs (uniform addresses via
// readfirstlane; SGPR_Count=96 confirms they scalarize). e1 staged per 64-s
// chunk, XOR-swizzled (conflict-free write+read). 4 partials per (t,s)
// reduced in LDS with -2 folded. Softmax by waves 0/1.
// __launch_bounds__(512, 2): the SECOND arg is load-bearing. With no arg (R5)
// or (512) alone (R6) the allocator targeted 32 VGPRs (a phantom 16-waves/EU
// occupancy) and spilled pf[] -> 200 MB/dispatch scratch traffic. min-waves=2
// sets amdgpu-waves-per-eu floor -> VGPR budget 256 -> no spill.
__global__ __launch_bounds__(512, 2) void score_kernel(
    const float* __restrict__ e1g, const float* __restrict__ e2g,
    const float* __restrict__ vc,  float* __restrict__ P)
{
    __shared__ float4 sE1q[32 * 64];   // 32 KB, [hq][s^hq]
    __shared__ float  sScore[2 * 512]; // 4 KB
    __shared__ float  sPartC[8 * 64];  // 2 KB, [w][s]

    const int tid  = threadIdx.x;
    const int b    = blockIdx.x >> 8;
    const int t0   = (blockIdx.x & 255) * 2;
    const int w    = tid >> 6;
    const int lane = tid & 63;
    const int wu   = __builtin_amdgcn_readfirstlane(w);
    const int tU   = wu >> 2;          // t this wave serves
    const int qU   = wu & 3;           // h-quarter (quads qU*8 .. qU*8+7)

    // scalar operands: 8 vc quads + 8 e2 quads -> 64 SGPRs
    float4 vcs[8];
    float4 e2s[8];
    #pragma unroll
    for (int j = 0; j < 8; ++j) {
        vcs[j] = *(const float4*)&vc[(qU * 8 + j) * 4];
        e2s[j] = *(const float4*)&e2g[(b * SEQ + t0 + tU) * HDIM + (qU * 8 + j) * 4];
    }

    // prefetch e1 chunk 0
    float4 pf[4];
    #pragma unroll
    for (int j = 0; j < 4; ++j) {
        const int i = tid + j * 512;
        const int hq = i & 31, sl = i >> 5;
        pf[j] = *(const float4*)&e1g[(b * SEQ + sl) * HDIM + hq * 4];
    }

    for (int c = 0; c < 8; ++c) {
        __syncthreads();
        #pragma unroll
        for (int j = 0; j < 4; ++j) {
            const int i = tid + j * 512;
            const int hq = i & 31, sl = i >> 5;
            sE1q[hq * 64 + (sl ^ hq)] = pf[j];
        }
        if (c > 0 && tid < 128) {
            const int t = tid >> 6, s = tid & 63;
            const float r = sPartC[(t*4+0)*64 + s] + sPartC[(t*4+1)*64 + s]
                          + sPartC[(t*4+2)*64 + s] + sPartC[(t*4+3)*64 + s];
            sScore[t * 512 + (c - 1) * 64 + s] = -2.f * r;
        }
        __syncthreads();
        if (c < 7) {
            #pragma unroll
            for (int j = 0; j < 4; ++j) {
                const int i = tid + j * 512;
                const int hq = i & 31, sl = i >> 5;
                pf[j] = *(const float4*)&e1g[(b * SEQ + (c + 1) * 64 + sl) * HDIM + hq * 4];
            }
        }
        float acc = 0.f;
        #pragma unroll
        for (int j = 0; j < 8; ++j) {
            const int hq = qU * 8 + j;
            const float4 e1 = sE1q[hq * 64 + (lane ^ hq)];
            const float4 vv = vcs[j];
            const float4 e2 = e2s[j];
            const float f1 = fmaf(e1.x, e2.x, 1.f);
            const float f2 = fmaf(e1.y, e2.y, 1.f);
            const float f3 = fmaf(e1.z, e2.z, 1.f);
            const float f4 = fmaf(e1.w, e2.w, 1.f);
            const float f12 = f1 * f2, f34 = f3 * f4;
            const float n12 = fmaf(vv.x, f2, vv.y * f1);
            const float n34 = fmaf(vv.z, f4, vv.w * f3);
            const float num = fmaf(n12, f34, n34 * f12);
            acc = fmaf(num, __builtin_amdgcn_rcpf(f12 * f34), acc);
        }
        sPartC[w * 64 + lane] = acc;
    }
    __syncthreads();
    if (tid < 128) {
        const int t = tid >> 6, s = tid & 63;
        const float r = sPartC[(t*4+0)*64 + s] + sPartC[(t*4+1)*64 + s]
                      + sPartC[(t*4+2)*64 + s] + sPartC[(t*4+3)*64 + s];
        sScore[t * 512 + 7 * 64 + s] = -2.f * r;
    }
    __syncthreads();

    // softmax: wave 0 -> t0, wave 1 -> t0+1; write normalized P
    if (w < 2) {
        float v[8];
        float m = -1e30f;
        #pragma unroll
        for (int j = 0; j < 8; ++j) {
            v[j] = sScore[w * 512 + lane + j * 64];
            m = fmaxf(m, v[j]);
        }
        #pragma unroll
        for (int off = 32; off; off >>= 1) m = fmaxf(m, __shfl_xor(m, off));
        float sum = 0.f;
        #pragma unroll
        for (int j = 0; j < 8; ++j) {
            v[j] = __builtin_amdgcn_exp2f((v[j] - m) * LOG2E);
            sum += v[j];
        }
        #pragma unroll
        for (int off = 32; off; off >>= 1) sum += __shfl_xor(sum, off);
        const float inv = __builtin_amdgcn_rcpf(sum);
        float* Prow = &P[(b * SEQ + t0 + w) * SEQ];
        #pragma unroll
        for (int j = 0; j < 8; ++j)
            Prow[lane + j * 64] = v[j] * inv;
    }
}

// ---------------- Kernel C: out = P @ x (unchanged) ------------------------
__global__ __launch_bounds__(256) void pax_kernel(
    const float* __restrict__ P, const float* __restrict__ x,
    float* __restrict__ out)
{
    __shared__ float sX[128 * 64];     // 32 KB
    __shared__ float sP[128 * 17];     // 8.5 KB
    const int tid = threadIdx.x;
    const int b   = blockIdx.x >> 7;
    const int tt  = (blockIdx.x >> 2) & 31;   // 16-t tile
    const int dq  = blockIdx.x & 3;           // 64-d quarter
    const int w    = tid >> 6;
    const int lane = tid & 63;

    float acc[16];
    #pragma unroll
    for (int t = 0; t < 16; ++t) acc[t] = 0.f;

    for (int cc = 0; cc < 4; ++cc) {
        __syncthreads();
        // stage x: 128 s x 64 d
        #pragma unroll
        for (int j = 0; j < 8; ++j) {
            const int i = tid + j * 256;
            const int s = i >> 4, d4 = (i & 15) * 4;
            *(float4*)&sX[s * 64 + d4] =
                *(const float4*)&x[(b * SEQ + cc * 128 + s) * DDIM + dq * 64 + d4];
        }
        // stage P transposed: read [t][s] coalesced, write [s][t] pad 17
        #pragma unroll
        for (int j = 0; j < 2; ++j) {
            const int i = tid + j * 256;          // [0,512): 4 t x 128 s
            const int t = i >> 7, s = i & 127;
            #pragma unroll
            for (int t4 = 0; t4 < 4; ++t4)
                sP[s * 17 + t4 * 4 + t] =
                    P[(b * SEQ + tt * 16 + t4 * 4 + t) * SEQ + cc * 128 + s];
        }
        __syncthreads();
        #pragma unroll 4
        for (int si = 0; si < 32; ++si) {
            const int s = w * 32 + si;
            const float xv = sX[s * 64 + lane];
            const float4 p0 = *(const float4*)&sP[s * 17 + 0];
            const float4 p1 = *(const float4*)&sP[s * 17 + 4];
            const float4 p2 = *(const float4*)&sP[s * 17 + 8];
            const float4 p3 = *(const float4*)&sP[s * 17 + 12];
            acc[ 0] = fmaf(p0.x, xv, acc[ 0]); acc[ 1] = fmaf(p0.y, xv, acc[ 1]);
            acc[ 2] = fmaf(p0.z, xv, acc[ 2]); acc[ 3] = fmaf(p0.w, xv, acc[ 3]);
            acc[ 4] = fmaf(p1.x, xv, acc[ 4]); acc[ 5] = fmaf(p1.y, xv, acc[ 5]);
            acc[ 6] = fmaf(p1.z, xv, acc[ 6]); acc[ 7] = fmaf(p1.w, xv, acc[ 7]);
            acc[ 8] = fmaf(p2.x, xv, acc[ 8]); acc[ 9] = fmaf(p2.y, xv, acc[ 9]);
            acc[10] = fmaf(p2.z, xv, acc[10]); acc[11] = fmaf(p2.w, xv, acc[11]);
            acc[12] = fmaf(p3.x, xv, acc[12]); acc[13] = fmaf(p3.y, xv, acc[13]);
            acc[14] = fmaf(p3.z, xv, acc[14]); acc[15] = fmaf(p3.w, xv, acc[15]);
        }
    }
    __syncthreads();
    float* sRed = sX;                  // reuse: [4 w][16 t][64 d] = 16 KB
    #pragma unroll
    for (int t = 0; t < 16; ++t)
        sRed[w * 1024 + t * 64 + lane] = acc[t];
    __syncthreads();
    #pragma unroll
    for (int j = 0; j < 4; ++j) {
        const int i = tid + j * 256;   // [0,1024): 16 t x 64 d
        const int t = i >> 6, d = i & 63;
        const float r = sRed[0*1024 + t*64 + d] + sRed[1*1024 + t*64 + d]
                      + sRed[2*1024 + t*64 + d] + sRed[3*1024 + t*64 + d];
        out[(b * SEQ + tt * 16 + t) * DDIM + dq * 64 + d] = r;
    }
}

extern "C" void kernel_launch(void* const* d_in, const int* in_sizes, int n_in,
                              void* d_out, int out_size, void* d_ws, size_t ws_size,
                              hipStream_t stream) {
    const float* x   = (const float*)d_in[0];   // (4,512,256)
    const float* y   = (const float*)d_in[1];   // (4,512,256)
    const float* W1  = (const float*)d_in[2];   // (128,256)
    const float* W2  = (const float*)d_in[3];   // (128,256)
    const float* vc  = (const float*)d_in[4];   // (1,128)
    float* outp = (float*)d_out;                // (4,512,256)

    float* ws   = (float*)d_ws;
    float* e1   = ws;                           // 1 MB
    float* e2   = ws + NB * SEQ * HDIM;         // 1 MB
    float* part = ws + 2 * NB * SEQ * HDIM;     // 4 MB
    float* P    = ws + 2 * NB * SEQ * HDIM + 2 * 4096 * HDIM;  // 4 MB

    hipLaunchKernelGGL(proj_part_kernel,    dim3(1024), dim3(256), 0, stream,
                       x, y, W1, W2, part);
    hipLaunchKernelGGL(proj_combine_kernel, dim3(512),  dim3(256), 0, stream,
                       part, e1, e2);
    hipLaunchKernelGGL(score_kernel,        dim3(1024), dim3(512), 0, stream,
                       e1, e2, vc, P);
    hipLaunchKernelGGL(pax_kernel,          dim3(512),  dim3(256), 0, stream,
                       P, x, outp);
}

// Round 8
// 122.839 us; speedup vs baseline: 1.3918x; 1.3884x over previous
//
#include <hip/hip_runtime.h>

// B=4, Sx=Sy=512, H=128, D=2H=256, fp32.
// e1 = exp2(2log2e * x@W1^T)  (stored PRE-SWIZZLED: [b][c][hq][s^hq] float4)
// e2 = exp2(2log2e * y@W2^T)  (linear)
// tanh(s1+s2) = 1 - 2/(e1*e2+1); score = sum_h vc[h]*tanh(.)
// constant sum_h vc[h] dropped (softmax shift-invariant); -2 folded into the
// cross-wave partial reduce. P = softmax_s(score); out = P @ x.
// Quad-rcp: v1/f1+..+v4/f4 = (n12*f34+n34*f12)/(f12*f34), one rcp per 4 h.
//
// R5-R7 lesson: allocator pins this kernel at 32 VGPRs regardless of
// __launch_bounds__ and spills any prefetch registers (200 MB/dispatch of
// scratch). Fix: no staging VGPRs at all — global_load_lds DMA (wave-uniform
// LDS base + lane*16), double-buffered, with e1 pre-swizzled in global so the
// DMA is a straight memcpy.

#define NB 4
#define SEQ 512
#define HDIM 128
#define DDIM 256

static constexpr float TWO_LOG2E = 2.8853900817779268f; // 2*log2(e)
static constexpr float LOG2E     = 1.4426950408889634f;

__device__ __forceinline__ void gload_lds16(const void* g, void* l) {
    __builtin_amdgcn_global_load_lds(
        (const __attribute__((address_space(1))) void*)g,
        (__attribute__((address_space(3))) void*)l, 16, 0, 0);
}

// ---------------- Kernel A1: partial projections (unchanged) ---------------
__global__ __launch_bounds__(256) void proj_part_kernel(
    const float* __restrict__ x, const float* __restrict__ y,
    const float* __restrict__ W1, const float* __restrict__ W2,
    float* __restrict__ part)
{
    __shared__ float As[1024];      // [8 r][128 k]
    __shared__ float sPr[8192];     // [8 ks][8 r][128 h]
    const int tid = threadIdx.x;
    const int blk = blockIdx.x;           // [0,1024)
    const int kq  = blk >> 9;             // k-half
    const int gr0 = (blk & 511) * 8;      // global row base [0,4096)

    const float* in; const float* W; int srow;
    if (gr0 < 2048) { in = x; W = W1; srow = gr0; }
    else            { in = y; W = W2; srow = gr0 - 2048; }

    {
        const int r = tid >> 5, kk = tid & 31;
        *(float4*)&As[tid * 4] =
            *(const float4*)&in[(srow + r) * 256 + kq * 128 + kk * 4];
    }
    __syncthreads();

    const int hq = tid & 31;
    const int ks = tid >> 5;

    float4 acc4[8];
    #pragma unroll
    for (int r = 0; r < 8; ++r) acc4[r] = make_float4(0.f, 0.f, 0.f, 0.f);

    #pragma unroll
    for (int u = 0; u < 4; ++u) {
        const int kof = kq * 128 + ks * 16 + u * 4;
        const float4 w0 = *(const float4*)&W[(4*hq + 0) * 256 + kof];
        const float4 w1 = *(const float4*)&W[(4*hq + 1) * 256 + kof];
        const float4 w2 = *(const float4*)&W[(4*hq + 2) * 256 + kof];
        const float4 w3 = *(const float4*)&W[(4*hq + 3) * 256 + kof];
        #pragma unroll
        for (int r = 0; r < 8; ++r) {
            const float4 a = *(const float4*)&As[r * 128 + ks * 16 + u * 4];
            acc4[r].x = fmaf(a.w,w0.w, fmaf(a.z,w0.z, fmaf(a.y,w0.y, fmaf(a.x,w0.x, acc4[r].x))));
            acc4[r].y = fmaf(a.w,w1.w, fmaf(a.z,w1.z, fmaf(a.y,w1.y, fmaf(a.x,w1.x, acc4[r].y))));
            acc4[r].z = fmaf(a.w,w2.w, fmaf(a.z,w2.z, fmaf(a.y,w2.y, fmaf(a.x,w2.x, acc4[r].z))));
            acc4[r].w = fmaf(a.w,w3.w, fmaf(a.z,w3.z, fmaf(a.y,w3.y, fmaf(a.x,w3.x, acc4[r].w))));
        }
    }
    #pragma unroll
    for (int r = 0; r < 8; ++r)
        *(float4*)&sPr[ks * 1024 + r * 128 + hq * 4] = acc4[r];
    __syncthreads();
    {
        const int r = tid >> 5, h4 = (tid & 31) * 4;
        float4 s = make_float4(0.f, 0.f, 0.f, 0.f);
        #pragma unroll
        for (int k2 = 0; k2 < 8; ++k2) {
            const float4 p = *(const float4*)&sPr[k2 * 1024 + r * 128 + h4];
            s.x += p.x; s.y += p.y; s.z += p.z; s.w += p.w;
        }
        *(float4*)&part[kq * 524288 + (gr0 + r) * 128 + h4] = s;
    }
}

// ---------------- Kernel A2: combine + exp2; e1 written swizzled -----------
// e1sw float4 layout: [b][c in 0..7][hq in 0..31][s^hq] — the exact LDS image
// score_kernel wants, so its staging is a linear DMA copy.
__global__ __launch_bounds__(256) void proj_combine_kernel(
    const float* __restrict__ part,
    float* __restrict__ e1sw, float* __restrict__ e2)
{
    const int j = blockIdx.x * 256 + threadIdx.x;   // float4 idx [0,131072)
    const float4 p0 = ((const float4*)part)[j];
    const float4 p1 = ((const float4*)part)[j + 131072];
    float4 o;
    o.x = __builtin_amdgcn_exp2f((p0.x + p1.x) * TWO_LOG2E);
    o.y = __builtin_amdgcn_exp2f((p0.y + p1.y) * TWO_LOG2E);
    o.z = __builtin_amdgcn_exp2f((p0.z + p1.z) * TWO_LOG2E);
    o.w = __builtin_amdgcn_exp2f((p0.w + p1.w) * TWO_LOG2E);
    const int gr = j >> 5;          // virtual row [0,4096)
    const int hq = j & 31;
    if (gr < 2048) {
        const int b = gr >> 9, s = gr & 511;
        const int c = s >> 6, sl = s & 63;
        ((float4*)e1sw)[((b * 8 + c) * 32 + hq) * 64 + (sl ^ hq)] = o;
    } else {
        ((float4*)e2)[j - 65536] = o;
    }
}

// ---------------- Kernel B: scores + softmax -> P --------------------------
// 1024 blocks x 512 thr (8 waves). Block = (b, 2 t). Wave w: t = w>>2,
// h-quarter = w&3. e2/vc in SGPRs (uniform addrs via readfirstlane).
// e1 staged via global_load_lds (no VGPR round-trip -> nothing to spill),
// double-buffered: chunk c+1's DMA issued right after the barrier, in flight
// during chunk c's compute; the next barrier's vmcnt(0) drain is the fence.
// One barrier per chunk; sPartC double-buffered so the cross-wave reduce of
// chunk c-1 can't race chunk c's partial writes.
__global__ __launch_bounds__(512) void score_kernel(
    const float* __restrict__ e1sw, const float* __restrict__ e2g,
    const float* __restrict__ vc,  float* __restrict__ P)
{
    __shared__ float4 sE1[2][2048];    // 2 x 32 KB
    __shared__ float  sScore[2 * 512]; // 4 KB
    __shared__ float  sPartC[2][512];  // 2 x 2 KB, [w][lane]

    const int tid  = threadIdx.x;
    const int b    = blockIdx.x >> 8;
    const int t0   = (blockIdx.x & 255) * 2;
    const int w    = tid >> 6;
    const int lane = tid & 63;
    const int wu   = __builtin_amdgcn_readfirstlane(w);
    const int tU   = wu >> 2;          // t this wave serves
    const int qU   = wu & 3;           // h-quarter (quads qU*8 .. qU*8+7)

    // scalar operands: 8 vc quads + 8 e2 quads -> SGPRs
    float4 vcs[8];
    float4 e2s[8];
    #pragma unroll
    for (int j = 0; j < 8; ++j) {
        vcs[j] = *(const float4*)&vc[(qU * 8 + j) * 4];
        e2s[j] = *(const float4*)&e2g[(b * SEQ + t0 + tU) * HDIM + (qU * 8 + j) * 4];
    }

    const float4* e1c = (const float4*)e1sw + b * 16384;  // 8 chunks x 2048

    // issue chunk 0 DMA into buf 0 (4 x 1KB segments per wave)
    #pragma unroll
    for (int j = 0; j < 4; ++j) {
        const int seg = wu * 256 + j * 64;
        gload_lds16(e1c + seg + lane, &sE1[0][seg]);
    }

    for (int c = 0; c < 8; ++c) {
        __syncthreads();   // drains DMA: buf[c&1] ready; epoch boundary
        if (c < 7) {
            const float4* gch = e1c + (c + 1) * 2048;
            #pragma unroll
            for (int j = 0; j < 4; ++j) {
                const int seg = wu * 256 + j * 64;
                gload_lds16(gch + seg + lane, &sE1[(c + 1) & 1][seg]);
            }
        }
        if (c > 0 && tid < 128) {
            const int t = tid >> 6, s = tid & 63;
            const float* pc = sPartC[(c - 1) & 1];
            const float r = pc[(t*4+0)*64 + s] + pc[(t*4+1)*64 + s]
                          + pc[(t*4+2)*64 + s] + pc[(t*4+3)*64 + s];
            sScore[t * 512 + (c - 1) * 64 + s] = -2.f * r;
        }
        float acc = 0.f;
        const float4* buf = sE1[c & 1];
        #pragma unroll
        for (int j = 0; j < 8; ++j) {
            const int hq = qU * 8 + j;
            const float4 e1 = buf[hq * 64 + (lane ^ hq)];
            const float4 vv = vcs[j];
            const float4 e2 = e2s[j];
            const float f1 = fmaf(e1.x, e2.x, 1.f);
            const float f2 = fmaf(e1.y, e2.y, 1.f);
            const float f3 = fmaf(e1.z, e2.z, 1.f);
            const float f4 = fmaf(e1.w, e2.w, 1.f);
            const float f12 = f1 * f2, f34 = f3 * f4;
            const float n12 = fmaf(vv.x, f2, vv.y * f1);
            const float n34 = fmaf(vv.z, f4, vv.w * f3);
            const float num = fmaf(n12, f34, n34 * f12);
            acc = fmaf(num, __builtin_amdgcn_rcpf(f12 * f34), acc);
        }
        sPartC[c & 1][w * 64 + lane] = acc;
    }
    __syncthreads();
    if (tid < 128) {
        const int t = tid >> 6, s = tid & 63;
        const float* pc = sPartC[7 & 1];
        const float r = pc[(t*4+0)*64 + s] + pc[(t*4+1)*64 + s]
                      + pc[(t*4+2)*64 + s] + pc[(t*4+3)*64 + s];
        sScore[t * 512 + 7 * 64 + s] = -2.f * r;
    }
    __syncthreads();

    // softmax: wave 0 -> t0, wave 1 -> t0+1; write normalized P
    if (w < 2) {
        float v[8];
        float m = -1e30f;
        #pragma unroll
        for (int j = 0; j < 8; ++j) {
            v[j] = sScore[w * 512 + lane + j * 64];
            m = fmaxf(m, v[j]);
        }
        #pragma unroll
        for (int off = 32; off; off >>= 1) m = fmaxf(m, __shfl_xor(m, off));
        float sum = 0.f;
        #pragma unroll
        for (int j = 0; j < 8; ++j) {
            v[j] = __builtin_amdgcn_exp2f((v[j] - m) * LOG2E);
            sum += v[j];
        }
        #pragma unroll
        for (int off = 32; off; off >>= 1) sum += __shfl_xor(sum, off);
        const float inv = __builtin_amdgcn_rcpf(sum);
        float* Prow = &P[(b * SEQ + t0 + w) * SEQ];
        #pragma unroll
        for (int j = 0; j < 8; ++j)
            Prow[lane + j * 64] = v[j] * inv;
    }
}

// ---------------- Kernel C: out = P @ x (unchanged) ------------------------
__global__ __launch_bounds__(256) void pax_kernel(
    const float* __restrict__ P, const float* __restrict__ x,
    float* __restrict__ out)
{
    __shared__ float sX[128 * 64];     // 32 KB
    __shared__ float sP[128 * 17];     // 8.5 KB
    const int tid = threadIdx.x;
    const int b   = blockIdx.x >> 7;
    const int tt  = (blockIdx.x >> 2) & 31;   // 16-t tile
    const int dq  = blockIdx.x & 3;           // 64-d quarter
    const int w    = tid >> 6;
    const int lane = tid & 63;

    float acc[16];
    #pragma unroll
    for (int t = 0; t < 16; ++t) acc[t] = 0.f;

    for (int cc = 0; cc < 4; ++cc) {
        __syncthreads();
        #pragma unroll
        for (int j = 0; j < 8; ++j) {
            const int i = tid + j * 256;
            const int s = i >> 4, d4 = (i & 15) * 4;
            *(float4*)&sX[s * 64 + d4] =
                *(const float4*)&x[(b * SEQ + cc * 128 + s) * DDIM + dq * 64 + d4];
        }
        #pragma unroll
        for (int j = 0; j < 2; ++j) {
            const int i = tid + j * 256;          // [0,512): 4 t x 128 s
            const int t = i >> 7, s = i & 127;
            #pragma unroll
            for (int t4 = 0; t4 < 4; ++t4)
                sP[s * 17 + t4 * 4 + t] =
                    P[(b * SEQ + tt * 16 + t4 * 4 + t) * SEQ + cc * 128 + s];
        }
        __syncthreads();
        #pragma unroll 4
        for (int si = 0; si < 32; ++si) {
            const int s = w * 32 + si;
            const float xv = sX[s * 64 + lane];
            const float4 p0 = *(const float4*)&sP[s * 17 + 0];
            const float4 p1 = *(const float4*)&sP[s * 17 + 4];
            const float4 p2 = *(const float4*)&sP[s * 17 + 8];
            const float4 p3 = *(const float4*)&sP[s * 17 + 12];
            acc[ 0] = fmaf(p0.x, xv, acc[ 0]); acc[ 1] = fmaf(p0.y, xv, acc[ 1]);
            acc[ 2] = fmaf(p0.z, xv, acc[ 2]); acc[ 3] = fmaf(p0.w, xv, acc[ 3]);
            acc[ 4] = fmaf(p1.x, xv, acc[ 4]); acc[ 5] = fmaf(p1.y, xv, acc[ 5]);
            acc[ 6] = fmaf(p1.z, xv, acc[ 6]); acc[ 7] = fmaf(p1.w, xv, acc[ 7]);
            acc[ 8] = fmaf(p2.x, xv, acc[ 8]); acc[ 9] = fmaf(p2.y, xv, acc[ 9]);
            acc[10] = fmaf(p2.z, xv, acc[10]); acc[11] = fmaf(p2.w, xv, acc[11]);
            acc[12] = fmaf(p3.x, xv, acc[12]); acc[13] = fmaf(p3.y, xv, acc[13]);
            acc[14] = fmaf(p3.z, xv, acc[14]); acc[15] = fmaf(p3.w, xv, acc[15]);
        }
    }
    __syncthreads();
    float* sRed = sX;                  // reuse: [4 w][16 t][64 d] = 16 KB
    #pragma unroll
    for (int t = 0; t < 16; ++t)
        sRed[w * 1024 + t * 64 + lane] = acc[t];
    __syncthreads();
    #pragma unroll
    for (int j = 0; j < 4; ++j) {
        const int i = tid + j * 256;   // [0,1024): 16 t x 64 d
        const int t = i >> 6, d = i & 63;
        const float r = sRed[0*1024 + t*64 + d] + sRed[1*1024 + t*64 + d]
                      + sRed[2*1024 + t*64 + d] + sRed[3*1024 + t*64 + d];
        out[(b * SEQ + tt * 16 + t) * DDIM + dq * 64 + d] = r;
    }
}

extern "C" void kernel_launch(void* const* d_in, const int* in_sizes, int n_in,
                              void* d_out, int out_size, void* d_ws, size_t ws_size,
                              hipStream_t stream) {
    const float* x   = (const float*)d_in[0];   // (4,512,256)
    const float* y   = (const float*)d_in[1];   // (4,512,256)
    const float* W1  = (const float*)d_in[2];   // (128,256)
    const float* W2  = (const float*)d_in[3];   // (128,256)
    const float* vc  = (const float*)d_in[4];   // (1,128)
    float* outp = (float*)d_out;                // (4,512,256)

    float* ws   = (float*)d_ws;
    float* e1   = ws;                           // 1 MB (swizzled)
    float* e2   = ws + NB * SEQ * HDIM;         // 1 MB
    float* part = ws + 2 * NB * SEQ * HDIM;     // 4 MB
    float* P    = ws + 2 * NB * SEQ * HDIM + 2 * 4096 * HDIM;  // 4 MB

    hipLaunchKernelGGL(proj_part_kernel,    dim3(1024), dim3(256), 0, stream,
                       x, y, W1, W2, part);
    hipLaunchKernelGGL(proj_combine_kernel, dim3(512),  dim3(256), 0, stream,
                       part, e1, e2);
    hipLaunchKernelGGL(score_kernel,        dim3(1024), dim3(512), 0, stream,
                       e1, e2, vc, P);
    hipLaunchKernelGGL(pax_kernel,          dim3(512),  dim3(256), 0, stream,
                       P, x, outp);
}

// Round 9
// 116.522 us; speedup vs baseline: 1.4673x; 1.0542x over previous
//
#include <hip/hip_runtime.h>

// B=4, Sx=Sy=512, H=128, D=2H=256, fp32.
// e1 = exp2(2log2e * x@W1^T)  (stored PRE-SWIZZLED: [b][c][hq][s^hq] float4)
// e2 = exp2(2log2e * y@W2^T)  (linear)
// tanh(s1+s2) = 1 - 2/(e1*e2+1); score = sum_h vc[h]*tanh(.)
// constant sum_h vc[h] dropped (softmax shift-invariant); -2 folded into the
// cross-wave partial reduce. P = softmax_s(score); out = P @ x.
// Quad-rcp: v1/f1+..+v4/f4 = (n12*f34+n34*f12)/(f12*f34), one rcp per 4 h.
//
// R5-R7: allocator pins 512-thr kernels at 32 VGPRs regardless of
// __launch_bounds__ and spills prefetch regs. Fix: global_load_lds DMA
// (zero staging VGPRs), e1 pre-swizzled in global so the DMA is a memcpy.
// R8: harness's 268 MB d_ws 0xAA fill = 42 us of the timed window (fixed).
// R9: pax rewritten — old version issued 5 LDS instr / 16 FMAs (~23 us,
// LDS-issue-bound); new shape does 1 global b128 + 2 LDS b128 / 32 FMAs.

#define NB 4
#define SEQ 512
#define HDIM 128
#define DDIM 256

static constexpr float TWO_LOG2E = 2.8853900817779268f; // 2*log2(e)
static constexpr float LOG2E     = 1.4426950408889634f;

__device__ __forceinline__ void gload_lds16(const void* g, void* l) {
    __builtin_amdgcn_global_load_lds(
        (const __attribute__((address_space(1))) void*)g,
        (__attribute__((address_space(3))) void*)l, 16, 0, 0);
}

// ---------------- Kernel A1: partial projections (unchanged) ---------------
__global__ __launch_bounds__(256) void proj_part_kernel(
    const float* __restrict__ x, const float* __restrict__ y,
    const float* __restrict__ W1, const float* __restrict__ W2,
    float* __restrict__ part)
{
    __shared__ float As[1024];      // [8 r][128 k]
    __shared__ float sPr[8192];     // [8 ks][8 r][128 h]
    const int tid = threadIdx.x;
    const int blk = blockIdx.x;           // [0,1024)
    const int kq  = blk >> 9;             // k-half
    const int gr0 = (blk & 511) * 8;      // global row base [0,4096)

    const float* in; const float* W; int srow;
    if (gr0 < 2048) { in = x; W = W1; srow = gr0; }
    else            { in = y; W = W2; srow = gr0 - 2048; }

    {
        const int r = tid >> 5, kk = tid & 31;
        *(float4*)&As[tid * 4] =
            *(const float4*)&in[(srow + r) * 256 + kq * 128 + kk * 4];
    }
    __syncthreads();

    const int hq = tid & 31;
    const int ks = tid >> 5;

    float4 acc4[8];
    #pragma unroll
    for (int r = 0; r < 8; ++r) acc4[r] = make_float4(0.f, 0.f, 0.f, 0.f);

    #pragma unroll
    for (int u = 0; u < 4; ++u) {
        const int kof = kq * 128 + ks * 16 + u * 4;
        const float4 w0 = *(const float4*)&W[(4*hq + 0) * 256 + kof];
        const float4 w1 = *(const float4*)&W[(4*hq + 1) * 256 + kof];
        const float4 w2 = *(const float4*)&W[(4*hq + 2) * 256 + kof];
        const float4 w3 = *(const float4*)&W[(4*hq + 3) * 256 + kof];
        #pragma unroll
        for (int r = 0; r < 8; ++r) {
            const float4 a = *(const float4*)&As[r * 128 + ks * 16 + u * 4];
            acc4[r].x = fmaf(a.w,w0.w, fmaf(a.z,w0.z, fmaf(a.y,w0.y, fmaf(a.x,w0.x, acc4[r].x))));
            acc4[r].y = fmaf(a.w,w1.w, fmaf(a.z,w1.z, fmaf(a.y,w1.y, fmaf(a.x,w1.x, acc4[r].y))));
            acc4[r].z = fmaf(a.w,w2.w, fmaf(a.z,w2.z, fmaf(a.y,w2.y, fmaf(a.x,w2.x, acc4[r].z))));
            acc4[r].w = fmaf(a.w,w3.w, fmaf(a.z,w3.z, fmaf(a.y,w3.y, fmaf(a.x,w3.x, acc4[r].w))));
        }
    }
    #pragma unroll
    for (int r = 0; r < 8; ++r)
        *(float4*)&sPr[ks * 1024 + r * 128 + hq * 4] = acc4[r];
    __syncthreads();
    {
        const int r = tid >> 5, h4 = (tid & 31) * 4;
        float4 s = make_float4(0.f, 0.f, 0.f, 0.f);
        #pragma unroll
        for (int k2 = 0; k2 < 8; ++k2) {
            const float4 p = *(const float4*)&sPr[k2 * 1024 + r * 128 + h4];
            s.x += p.x; s.y += p.y; s.z += p.z; s.w += p.w;
        }
        *(float4*)&part[kq * 524288 + (gr0 + r) * 128 + h4] = s;
    }
}

// ---------------- Kernel A2: combine + exp2; e1 written swizzled -----------
__global__ __launch_bounds__(256) void proj_combine_kernel(
    const float* __restrict__ part,
    float* __restrict__ e1sw, float* __restrict__ e2)
{
    const int j = blockIdx.x * 256 + threadIdx.x;   // float4 idx [0,131072)
    const float4 p0 = ((const float4*)part)[j];
    const float4 p1 = ((const float4*)part)[j + 131072];
    float4 o;
    o.x = __builtin_amdgcn_exp2f((p0.x + p1.x) * TWO_LOG2E);
    o.y = __builtin_amdgcn_exp2f((p0.y + p1.y) * TWO_LOG2E);
    o.z = __builtin_amdgcn_exp2f((p0.z + p1.z) * TWO_LOG2E);
    o.w = __builtin_amdgcn_exp2f((p0.w + p1.w) * TWO_LOG2E);
    const int gr = j >> 5;          // virtual row [0,4096)
    const int hq = j & 31;
    if (gr < 2048) {
        const int b = gr >> 9, s = gr & 511;
        const int c = s >> 6, sl = s & 63;
        ((float4*)e1sw)[((b * 8 + c) * 32 + hq) * 64 + (sl ^ hq)] = o;
    } else {
        ((float4*)e2)[j - 65536] = o;
    }
}

// ---------------- Kernel B: scores + softmax -> P (unchanged) --------------
__global__ __launch_bounds__(512) void score_kernel(
    const float* __restrict__ e1sw, const float* __restrict__ e2g,
    const float* __restrict__ vc,  float* __restrict__ P)
{
    __shared__ float4 sE1[2][2048];    // 2 x 32 KB
    __shared__ float  sScore[2 * 512]; // 4 KB
    __shared__ float  sPartC[2][512];  // 2 x 2 KB, [w][lane]

    const int tid  = threadIdx.x;
    const int b    = blockIdx.x >> 8;
    const int t0   = (blockIdx.x & 255) * 2;
    const int w    = tid >> 6;
    const int lane = tid & 63;
    const int wu   = __builtin_amdgcn_readfirstlane(w);
    const int tU   = wu >> 2;          // t this wave serves
    const int qU   = wu & 3;           // h-quarter (quads qU*8 .. qU*8+7)

    float4 vcs[8];
    float4 e2s[8];
    #pragma unroll
    for (int j = 0; j < 8; ++j) {
        vcs[j] = *(const float4*)&vc[(qU * 8 + j) * 4];
        e2s[j] = *(const float4*)&e2g[(b * SEQ + t0 + tU) * HDIM + (qU * 8 + j) * 4];
    }

    const float4* e1c = (const float4*)e1sw + b * 16384;  // 8 chunks x 2048

    #pragma unroll
    for (int j = 0; j < 4; ++j) {
        const int seg = wu * 256 + j * 64;
        gload_lds16(e1c + seg + lane, &sE1[0][seg]);
    }

    for (int c = 0; c < 8; ++c) {
        __syncthreads();   // drains DMA: buf[c&1] ready
        if (c < 7) {
            const float4* gch = e1c + (c + 1) * 2048;
            #pragma unroll
            for (int j = 0; j < 4; ++j) {
                const int seg = wu * 256 + j * 64;
                gload_lds16(gch + seg + lane, &sE1[(c + 1) & 1][seg]);
            }
        }
        if (c > 0 && tid < 128) {
            const int t = tid >> 6, s = tid & 63;
            const float* pc = sPartC[(c - 1) & 1];
            const float r = pc[(t*4+0)*64 + s] + pc[(t*4+1)*64 + s]
                          + pc[(t*4+2)*64 + s] + pc[(t*4+3)*64 + s];
            sScore[t * 512 + (c - 1) * 64 + s] = -2.f * r;
        }
        float acc = 0.f;
        const float4* buf = sE1[c & 1];
        #pragma unroll
        for (int j = 0; j < 8; ++j) {
            const int hq = qU * 8 + j;
            const float4 e1 = buf[hq * 64 + (lane ^ hq)];
            const float4 vv = vcs[j];
            const float4 e2 = e2s[j];
            const float f1 = fmaf(e1.x, e2.x, 1.f);
            const float f2 = fmaf(e1.y, e2.y, 1.f);
            const float f3 = fmaf(e1.z, e2.z, 1.f);
            const float f4 = fmaf(e1.w, e2.w, 1.f);
            const float f12 = f1 * f2, f34 = f3 * f4;
            const float n12 = fmaf(vv.x, f2, vv.y * f1);
            const float n34 = fmaf(vv.z, f4, vv.w * f3);
            const float num = fmaf(n12, f34, n34 * f12);
            acc = fmaf(num, __builtin_amdgcn_rcpf(f12 * f34), acc);
        }
        sPartC[c & 1][w * 64 + lane] = acc;
    }
    __syncthreads();
    if (tid < 128) {
        const int t = tid >> 6, s = tid & 63;
        const float* pc = sPartC[7 & 1];
        const float r = pc[(t*4+0)*64 + s] + pc[(t*4+1)*64 + s]
                      + pc[(t*4+2)*64 + s] + pc[(t*4+3)*64 + s];
        sScore[t * 512 + 7 * 64 + s] = -2.f * r;
    }
    __syncthreads();

    if (w < 2) {
        float v[8];
        float m = -1e30f;
        #pragma unroll
        for (int j = 0; j < 8; ++j) {
            v[j] = sScore[w * 512 + lane + j * 64];
            m = fmaxf(m, v[j]);
        }
        #pragma unroll
        for (int off = 32; off; off >>= 1) m = fmaxf(m, __shfl_xor(m, off));
        float sum = 0.f;
        #pragma unroll
        for (int j = 0; j < 8; ++j) {
            v[j] = __builtin_amdgcn_exp2f((v[j] - m) * LOG2E);
            sum += v[j];
        }
        #pragma unroll
        for (int off = 32; off; off >>= 1) sum += __shfl_xor(sum, off);
        const float inv = __builtin_amdgcn_rcpf(sum);
        float* Prow = &P[(b * SEQ + t0 + w) * SEQ];
        #pragma unroll
        for (int j = 0; j < 8; ++j)
            Prow[lane + j * 64] = v[j] * inv;
    }
}

// ---------------- Kernel C: out = P @ x (rewritten) ------------------------
// 256 blocks x 256 thr. Block = (b, 8-t tile). Wave = s-quarter (128 s);
// lane = d-quad covering ALL 256 d. Per s: 1 global b128 (x, L2-hot) +
// 2 broadcast b128 (8 probs from sP[s][8t]) -> 32 FMAs. x never staged.
// P staged once: coalesced global read, stride-8 LDS scatter (one-time).
__global__ __launch_bounds__(256) void pax_kernel(
    const float* __restrict__ P, const float* __restrict__ x,
    float* __restrict__ out)
{
    __shared__ float sP[SEQ * 8];        // 16 KB: [s][t]
    __shared__ float sRed[4 * 8 * DDIM]; // 32 KB: [w][t][d]
    const int tid = threadIdx.x;
    const int b   = blockIdx.x >> 6;
    const int t0  = (blockIdx.x & 63) * 8;
    const int w    = tid >> 6;
    const int lane = tid & 63;

    // stage P[b, t0..t0+7, :] transposed -> sP[s*8 + t]
    #pragma unroll
    for (int j = 0; j < 4; ++j) {
        const int i = tid + j * 256;          // [0,1024): t = i>>7, c4 = i&127
        const int t = i >> 7, c4 = i & 127;
        const float4 p = *(const float4*)&P[(b * SEQ + t0 + t) * SEQ + c4 * 4];
        sP[(c4 * 4 + 0) * 8 + t] = p.x;
        sP[(c4 * 4 + 1) * 8 + t] = p.y;
        sP[(c4 * 4 + 2) * 8 + t] = p.z;
        sP[(c4 * 4 + 3) * 8 + t] = p.w;
    }
    __syncthreads();

    const float4* x4 = (const float4*)x;
    float4 acc[8];
    #pragma unroll
    for (int t = 0; t < 8; ++t) acc[t] = make_float4(0.f, 0.f, 0.f, 0.f);

    #pragma unroll 4
    for (int si = 0; si < 128; ++si) {
        const int s = w * 128 + si;
        const float4 xv  = x4[(b * SEQ + s) * 64 + lane];
        const float4 p03 = *(const float4*)&sP[s * 8];
        const float4 p47 = *(const float4*)&sP[s * 8 + 4];
        acc[0].x = fmaf(p03.x, xv.x, acc[0].x); acc[0].y = fmaf(p03.x, xv.y, acc[0].y);
        acc[0].z = fmaf(p03.x, xv.z, acc[0].z); acc[0].w = fmaf(p03.x, xv.w, acc[0].w);
        acc[1].x = fmaf(p03.y, xv.x, acc[1].x); acc[1].y = fmaf(p03.y, xv.y, acc[1].y);
        acc[1].z = fmaf(p03.y, xv.z, acc[1].z); acc[1].w = fmaf(p03.y, xv.w, acc[1].w);
        acc[2].x = fmaf(p03.z, xv.x, acc[2].x); acc[2].y = fmaf(p03.z, xv.y, acc[2].y);
        acc[2].z = fmaf(p03.z, xv.z, acc[2].z); acc[2].w = fmaf(p03.z, xv.w, acc[2].w);
        acc[3].x = fmaf(p03.w, xv.x, acc[3].x); acc[3].y = fmaf(p03.w, xv.y, acc[3].y);
        acc[3].z = fmaf(p03.w, xv.z, acc[3].z); acc[3].w = fmaf(p03.w, xv.w, acc[3].w);
        acc[4].x = fmaf(p47.x, xv.x, acc[4].x); acc[4].y = fmaf(p47.x, xv.y, acc[4].y);
        acc[4].z = fmaf(p47.x, xv.z, acc[4].z); acc[4].w = fmaf(p47.x, xv.w, acc[4].w);
        acc[5].x = fmaf(p47.y, xv.x, acc[5].x); acc[5].y = fmaf(p47.y, xv.y, acc[5].y);
        acc[5].z = fmaf(p47.y, xv.z, acc[5].z); acc[5].w = fmaf(p47.y, xv.w, acc[5].w);
        acc[6].x = fmaf(p47.z, xv.x, acc[6].x); acc[6].y = fmaf(p47.z, xv.y, acc[6].y);
        acc[6].z = fmaf(p47.z, xv.z, acc[6].z); acc[6].w = fmaf(p47.z, xv.w, acc[6].w);
        acc[7].x = fmaf(p47.w, xv.x, acc[7].x); acc[7].y = fmaf(p47.w, xv.y, acc[7].y);
        acc[7].z = fmaf(p47.w, xv.z, acc[7].z); acc[7].w = fmaf(p47.w, xv.w, acc[7].w);
    }
    __syncthreads();
    float4* sRed4 = (float4*)sRed;     // [4 w][8 t][64 lanes]
    #pragma unroll
    for (int t = 0; t < 8; ++t)
        sRed4[w * 512 + t * 64 + lane] = acc[t];
    __syncthreads();
    #pragma unroll
    for (int j = 0; j < 8; ++j) {
        const int i = tid + j * 256;   // [0,2048): t = i>>8, d = i&255
        const int t = i >> 8, d = i & 255;
        const float r = sRed[0*2048 + t*256 + d] + sRed[1*2048 + t*256 + d]
                      + sRed[2*2048 + t*256 + d] + sRed[3*2048 + t*256 + d];
        out[(b * SEQ + t0 + t) * DDIM + d] = r;
    }
}

extern "C" void kernel_launch(void* const* d_in, const int* in_sizes, int n_in,
                              void* d_out, int out_size, void* d_ws, size_t ws_size,
                              hipStream_t stream) {
    const float* x   = (const float*)d_in[0];   // (4,512,256)
    const float* y   = (const float*)d_in[1];   // (4,512,256)
    const float* W1  = (const float*)d_in[2];   // (128,256)
    const float* W2  = (const float*)d_in[3];   // (128,256)
    const float* vc  = (const float*)d_in[4];   // (1,128)
    float* outp = (float*)d_out;                // (4,512,256)

    float* ws   = (float*)d_ws;
    float* e1   = ws;                           // 1 MB (swizzled)
    float* e2   = ws + NB * SEQ * HDIM;         // 1 MB
    float* part = ws + 2 * NB * SEQ * HDIM;     // 4 MB
    float* P    = ws + 2 * NB * SEQ * HDIM + 2 * 4096 * HDIM;  // 4 MB

    hipLaunchKernelGGL(proj_part_kernel,    dim3(1024), dim3(256), 0, stream,
                       x, y, W1, W2, part);
    hipLaunchKernelGGL(proj_combine_kernel, dim3(512),  dim3(256), 0, stream,
                       part, e1, e2);
    hipLaunchKernelGGL(score_kernel,        dim3(1024), dim3(512), 0, stream,
                       e1, e2, vc, P);
    hipLaunchKernelGGL(pax_kernel,          dim3(256),  dim3(256), 0, stream,
                       P, x, outp);
}

// Round 10
// 116.043 us; speedup vs baseline: 1.4733x; 1.0041x over previous
//
#include <hip/hip_runtime.h>

// B=4, Sx=Sy=512, H=128, D=2H=256, fp32.
// e1 = exp2(2log2e * x@W1^T)  (stored PRE-SWIZZLED: [b][c][hq][s^hq] float4)
// e2 = exp2(2log2e * y@W2^T)  (linear)
// tanh(s1+s2) = 1 - 2/(e1*e2+1); score = sum_h vc[h]*tanh(.)
// constant sum_h vc[h] dropped (softmax shift-invariant); -2 folded into the
// cross-wave partial reduce. P = softmax_s(score); out = P @ x.
// Quad-rcp: v1/f1+..+v4/f4 = (n12*f34+n34*f12)/(f12*f34), one rcp per 4 h.
//
// R5-R7: allocator pins 512-thr kernels at 32 VGPRs regardless of
// __launch_bounds__ and spills prefetch regs. Fix: global_load_lds DMA
// (zero staging VGPRs), e1 pre-swizzled in global so the DMA is a memcpy.
// R8: harness 256 MiB d_ws 0xAA fill = ~40 us of every timed iteration.
// R9: pax rewrite (1 b128 global + 2 b128 LDS per 32 FMAs) -> ~6 us gain.
// R10: score t=4/block (512 blk x 1024 thr): halves e1 L2 re-reads and
// barrier events; 32 waves/CU.

#define NB 4
#define SEQ 512
#define HDIM 128
#define DDIM 256

static constexpr float TWO_LOG2E = 2.8853900817779268f; // 2*log2(e)
static constexpr float LOG2E     = 1.4426950408889634f;

__device__ __forceinline__ void gload_lds16(const void* g, void* l) {
    __builtin_amdgcn_global_load_lds(
        (const __attribute__((address_space(1))) void*)g,
        (__attribute__((address_space(3))) void*)l, 16, 0, 0);
}

// ---------------- Kernel A1: partial projections (unchanged) ---------------
__global__ __launch_bounds__(256) void proj_part_kernel(
    const float* __restrict__ x, const float* __restrict__ y,
    const float* __restrict__ W1, const float* __restrict__ W2,
    float* __restrict__ part)
{
    __shared__ float As[1024];      // [8 r][128 k]
    __shared__ float sPr[8192];     // [8 ks][8 r][128 h]
    const int tid = threadIdx.x;
    const int blk = blockIdx.x;           // [0,1024)
    const int kq  = blk >> 9;             // k-half
    const int gr0 = (blk & 511) * 8;      // global row base [0,4096)

    const float* in; const float* W; int srow;
    if (gr0 < 2048) { in = x; W = W1; srow = gr0; }
    else            { in = y; W = W2; srow = gr0 - 2048; }

    {
        const int r = tid >> 5, kk = tid & 31;
        *(float4*)&As[tid * 4] =
            *(const float4*)&in[(srow + r) * 256 + kq * 128 + kk * 4];
    }
    __syncthreads();

    const int hq = tid & 31;
    const int ks = tid >> 5;

    float4 acc4[8];
    #pragma unroll
    for (int r = 0; r < 8; ++r) acc4[r] = make_float4(0.f, 0.f, 0.f, 0.f);

    #pragma unroll
    for (int u = 0; u < 4; ++u) {
        const int kof = kq * 128 + ks * 16 + u * 4;
        const float4 w0 = *(const float4*)&W[(4*hq + 0) * 256 + kof];
        const float4 w1 = *(const float4*)&W[(4*hq + 1) * 256 + kof];
        const float4 w2 = *(const float4*)&W[(4*hq + 2) * 256 + kof];
        const float4 w3 = *(const float4*)&W[(4*hq + 3) * 256 + kof];
        #pragma unroll
        for (int r = 0; r < 8; ++r) {
            const float4 a = *(const float4*)&As[r * 128 + ks * 16 + u * 4];
            acc4[r].x = fmaf(a.w,w0.w, fmaf(a.z,w0.z, fmaf(a.y,w0.y, fmaf(a.x,w0.x, acc4[r].x))));
            acc4[r].y = fmaf(a.w,w1.w, fmaf(a.z,w1.z, fmaf(a.y,w1.y, fmaf(a.x,w1.x, acc4[r].y))));
            acc4[r].z = fmaf(a.w,w2.w, fmaf(a.z,w2.z, fmaf(a.y,w2.y, fmaf(a.x,w2.x, acc4[r].z))));
            acc4[r].w = fmaf(a.w,w3.w, fmaf(a.z,w3.z, fmaf(a.y,w3.y, fmaf(a.x,w3.x, acc4[r].w))));
        }
    }
    #pragma unroll
    for (int r = 0; r < 8; ++r)
        *(float4*)&sPr[ks * 1024 + r * 128 + hq * 4] = acc4[r];
    __syncthreads();
    {
        const int r = tid >> 5, h4 = (tid & 31) * 4;
        float4 s = make_float4(0.f, 0.f, 0.f, 0.f);
        #pragma unroll
        for (int k2 = 0; k2 < 8; ++k2) {
            const float4 p = *(const float4*)&sPr[k2 * 1024 + r * 128 + h4];
            s.x += p.x; s.y += p.y; s.z += p.z; s.w += p.w;
        }
        *(float4*)&part[kq * 524288 + (gr0 + r) * 128 + h4] = s;
    }
}

// ---------------- Kernel A2: combine + exp2; e1 written swizzled -----------
__global__ __launch_bounds__(256) void proj_combine_kernel(
    const float* __restrict__ part,
    float* __restrict__ e1sw, float* __restrict__ e2)
{
    const int j = blockIdx.x * 256 + threadIdx.x;   // float4 idx [0,131072)
    const float4 p0 = ((const float4*)part)[j];
    const float4 p1 = ((const float4*)part)[j + 131072];
    float4 o;
    o.x = __builtin_amdgcn_exp2f((p0.x + p1.x) * TWO_LOG2E);
    o.y = __builtin_amdgcn_exp2f((p0.y + p1.y) * TWO_LOG2E);
    o.z = __builtin_amdgcn_exp2f((p0.z + p1.z) * TWO_LOG2E);
    o.w = __builtin_amdgcn_exp2f((p0.w + p1.w) * TWO_LOG2E);
    const int gr = j >> 5;          // virtual row [0,4096)
    const int hq = j & 31;
    if (gr < 2048) {
        const int b = gr >> 9, s = gr & 511;
        const int c = s >> 6, sl = s & 63;
        ((float4*)e1sw)[((b * 8 + c) * 32 + hq) * 64 + (sl ^ hq)] = o;
    } else {
        ((float4*)e2)[j - 65536] = o;
    }
}

// ---------------- Kernel B: scores + softmax -> P --------------------------
// 512 blocks x 1024 thr (16 waves). Block = (b, 4 t). Wave w: t = w>>2,
// h-quarter = w&3. e2/vc in SGPRs (uniform addrs via readfirstlane).
// e1 staged via global_load_lds DMA, double-buffered; each wave DMAs
// 2 x 1KB segments per chunk. 4 partials per (t,s) reduced in LDS with -2
// folded; sPartC double-buffered. Softmax by waves 0..3. LDS = 80 KB ->
// 2 blocks/CU = 32 waves/CU; grid covers all CUs in one pass.
__global__ __launch_bounds__(1024) void score_kernel(
    const float* __restrict__ e1sw, const float* __restrict__ e2g,
    const float* __restrict__ vc,  float* __restrict__ P)
{
    __shared__ float4 sE1[2][2048];     // 2 x 32 KB
    __shared__ float  sScore[4 * 512];  // 8 KB
    __shared__ float  sPartC[2][1024];  // 2 x 4 KB, [w][lane]

    const int tid  = threadIdx.x;
    const int b    = blockIdx.x >> 7;
    const int t0   = (blockIdx.x & 127) * 4;
    const int w    = tid >> 6;
    const int lane = tid & 63;
    const int wu   = __builtin_amdgcn_readfirstlane(w);
    const int tU   = wu >> 2;          // t this wave serves (0..3)
    const int qU   = wu & 3;           // h-quarter (quads qU*8 .. qU*8+7)

    // scalar operands: 8 vc quads + 8 e2 quads -> SGPRs
    float4 vcs[8];
    float4 e2s[8];
    #pragma unroll
    for (int j = 0; j < 8; ++j) {
        vcs[j] = *(const float4*)&vc[(qU * 8 + j) * 4];
        e2s[j] = *(const float4*)&e2g[(b * SEQ + t0 + tU) * HDIM + (qU * 8 + j) * 4];
    }

    const float4* e1c = (const float4*)e1sw + b * 16384;  // 8 chunks x 2048

    // issue chunk 0 DMA into buf 0 (2 x 1KB segments per wave)
    #pragma unroll
    for (int j = 0; j < 2; ++j) {
        const int seg = wu * 128 + j * 64;
        gload_lds16(e1c + seg + lane, &sE1[0][seg]);
    }

    for (int c = 0; c < 8; ++c) {
        __syncthreads();   // drains DMA: buf[c&1] ready
        if (c < 7) {
            const float4* gch = e1c + (c + 1) * 2048;
            #pragma unroll
            for (int j = 0; j < 2; ++j) {
                const int seg = wu * 128 + j * 64;
                gload_lds16(gch + seg + lane, &sE1[(c + 1) & 1][seg]);
            }
        }
        if (c > 0 && tid < 256) {
            const int t = tid >> 6, s = tid & 63;
            const float* pc = sPartC[(c - 1) & 1];
            const float r = pc[(t*4+0)*64 + s] + pc[(t*4+1)*64 + s]
                          + pc[(t*4+2)*64 + s] + pc[(t*4+3)*64 + s];
            sScore[t * 512 + (c - 1) * 64 + s] = -2.f * r;
        }
        float acc = 0.f;
        const float4* buf = sE1[c & 1];
        #pragma unroll
        for (int j = 0; j < 8; ++j) {
            const int hq = qU * 8 + j;
            const float4 e1 = buf[hq * 64 + (lane ^ hq)];
            const float4 vv = vcs[j];
            const float4 e2 = e2s[j];
            const float f1 = fmaf(e1.x, e2.x, 1.f);
            const float f2 = fmaf(e1.y, e2.y, 1.f);
            const float f3 = fmaf(e1.z, e2.z, 1.f);
            const float f4 = fmaf(e1.w, e2.w, 1.f);
            const float f12 = f1 * f2, f34 = f3 * f4;
            const float n12 = fmaf(vv.x, f2, vv.y * f1);
            const float n34 = fmaf(vv.z, f4, vv.w * f3);
            const float num = fmaf(n12, f34, n34 * f12);
            acc = fmaf(num, __builtin_amdgcn_rcpf(f12 * f34), acc);
        }
        sPartC[c & 1][w * 64 + lane] = acc;
    }
    __syncthreads();
    if (tid < 256) {
        const int t = tid >> 6, s = tid & 63;
        const float* pc = sPartC[7 & 1];
        const float r = pc[(t*4+0)*64 + s] + pc[(t*4+1)*64 + s]
                      + pc[(t*4+2)*64 + s] + pc[(t*4+3)*64 + s];
        sScore[t * 512 + 7 * 64 + s] = -2.f * r;
    }
    __syncthreads();

    // softmax: waves 0..3 -> t0+w; write normalized P
    if (w < 4) {
        float v[8];
        float m = -1e30f;
        #pragma unroll
        for (int j = 0; j < 8; ++j) {
            v[j] = sScore[w * 512 + lane + j * 64];
            m = fmaxf(m, v[j]);
        }
        #pragma unroll
        for (int off = 32; off; off >>= 1) m = fmaxf(m, __shfl_xor(m, off));
        float sum = 0.f;
        #pragma unroll
        for (int j = 0; j < 8; ++j) {
            v[j] = __builtin_amdgcn_exp2f((v[j] - m) * LOG2E);
            sum += v[j];
        }
        #pragma unroll
        for (int off = 32; off; off >>= 1) sum += __shfl_xor(sum, off);
        const float inv = __builtin_amdgcn_rcpf(sum);
        float* Prow = &P[(b * SEQ + t0 + w) * SEQ];
        #pragma unroll
        for (int j = 0; j < 8; ++j)
            Prow[lane + j * 64] = v[j] * inv;
    }
}

// ---------------- Kernel C: out = P @ x (unchanged from R9) ----------------
__global__ __launch_bounds__(256) void pax_kernel(
    const float* __restrict__ P, const float* __restrict__ x,
    float* __restrict__ out)
{
    __shared__ float sP[SEQ * 8];        // 16 KB: [s][t]
    __shared__ float sRed[4 * 8 * DDIM]; // 32 KB: [w][t][d]
    const int tid = threadIdx.x;
    const int b   = blockIdx.x >> 6;
    const int t0  = (blockIdx.x & 63) * 8;
    const int w    = tid >> 6;
    const int lane = tid & 63;

    #pragma unroll
    for (int j = 0; j < 4; ++j) {
        const int i = tid + j * 256;          // [0,1024): t = i>>7, c4 = i&127
        const int t = i >> 7, c4 = i & 127;
        const float4 p = *(const float4*)&P[(b * SEQ + t0 + t) * SEQ + c4 * 4];
        sP[(c4 * 4 + 0) * 8 + t] = p.x;
        sP[(c4 * 4 + 1) * 8 + t] = p.y;
        sP[(c4 * 4 + 2) * 8 + t] = p.z;
        sP[(c4 * 4 + 3) * 8 + t] = p.w;
    }
    __syncthreads();

    const float4* x4 = (const float4*)x;
    float4 acc[8];
    #pragma unroll
    for (int t = 0; t < 8; ++t) acc[t] = make_float4(0.f, 0.f, 0.f, 0.f);

    #pragma unroll 4
    for (int si = 0; si < 128; ++si) {
        const int s = w * 128 + si;
        const float4 xv  = x4[(b * SEQ + s) * 64 + lane];
        const float4 p03 = *(const float4*)&sP[s * 8];
        const float4 p47 = *(const float4*)&sP[s * 8 + 4];
        acc[0].x = fmaf(p03.x, xv.x, acc[0].x); acc[0].y = fmaf(p03.x, xv.y, acc[0].y);
        acc[0].z = fmaf(p03.x, xv.z, acc[0].z); acc[0].w = fmaf(p03.x, xv.w, acc[0].w);
        acc[1].x = fmaf(p03.y, xv.x, acc[1].x); acc[1].y = fmaf(p03.y, xv.y, acc[1].y);
        acc[1].z = fmaf(p03.y, xv.z, acc[1].z); acc[1].w = fmaf(p03.y, xv.w, acc[1].w);
        acc[2].x = fmaf(p03.z, xv.x, acc[2].x); acc[2].y = fmaf(p03.z, xv.y, acc[2].y);
        acc[2].z = fmaf(p03.z, xv.z, acc[2].z); acc[2].w = fmaf(p03.z, xv.w, acc[2].w);
        acc[3].x = fmaf(p03.w, xv.x, acc[3].x); acc[3].y = fmaf(p03.w, xv.y, acc[3].y);
        acc[3].z = fmaf(p03.w, xv.z, acc[3].z); acc[3].w = fmaf(p03.w, xv.w, acc[3].w);
        acc[4].x = fmaf(p47.x, xv.x, acc[4].x); acc[4].y = fmaf(p47.x, xv.y, acc[4].y);
        acc[4].z = fmaf(p47.x, xv.z, acc[4].z); acc[4].w = fmaf(p47.x, xv.w, acc[4].w);
        acc[5].x = fmaf(p47.y, xv.x, acc[5].x); acc[5].y = fmaf(p47.y, xv.y, acc[5].y);
        acc[5].z = fmaf(p47.y, xv.z, acc[5].z); acc[5].w = fmaf(p47.y, xv.w, acc[5].w);
        acc[6].x = fmaf(p47.z, xv.x, acc[6].x); acc[6].y = fmaf(p47.z, xv.y, acc[6].y);
        acc[6].z = fmaf(p47.z, xv.z, acc[6].z); acc[6].w = fmaf(p47.z, xv.w, acc[6].w);
        acc[7].x = fmaf(p47.w, xv.x, acc[7].x); acc[7].y = fmaf(p47.w, xv.y, acc[7].y);
        acc[7].z = fmaf(p47.w, xv.z, acc[7].z); acc[7].w = fmaf(p47.w, xv.w, acc[7].w);
    }
    __syncthreads();
    float4* sRed4 = (float4*)sRed;     // [4 w][8 t][64 lanes]
    #pragma unroll
    for (int t = 0; t < 8; ++t)
        sRed4[w * 512 + t * 64 + lane] = acc[t];
    __syncthreads();
    #pragma unroll
    for (int j = 0; j < 8; ++j) {
        const int i = tid + j * 256;   // [0,2048): t = i>>8, d = i&255
        const int t = i >> 8, d = i & 255;
        const float r = sRed[0*2048 + t*256 + d] + sRed[1*2048 + t*256 + d]
                      + sRed[2*2048 + t*256 + d] + sRed[3*2048 + t*256 + d];
        out[(b * SEQ + t0 + t) * DDIM + d] = r;
    }
}

extern "C" void kernel_launch(void* const* d_in, const int* in_sizes, int n_in,
                              void* d_out, int out_size, void* d_ws, size_t ws_size,
                              hipStream_t stream) {
    const float* x   = (const float*)d_in[0];   // (4,512,256)
    const float* y   = (const float*)d_in[1];   // (4,512,256)
    const float* W1  = (const float*)d_in[2];   // (128,256)
    const float* W2  = (const float*)d_in[3];   // (128,256)
    const float* vc  = (const float*)d_in[4];   // (1,128)
    float* outp = (float*)d_out;                // (4,512,256)

    float* ws   = (float*)d_ws;
    float* e1   = ws;                           // 1 MB (swizzled)
    float* e2   = ws + NB * SEQ * HDIM;         // 1 MB
    float* part = ws + 2 * NB * SEQ * HDIM;     // 4 MB
    float* P    = ws + 2 * NB * SEQ * HDIM + 2 * 4096 * HDIM;  // 4 MB

    hipLaunchKernelGGL(proj_part_kernel,    dim3(1024), dim3(256), 0, stream,
                       x, y, W1, W2, part);
    hipLaunchKernelGGL(proj_combine_kernel, dim3(512),  dim3(256), 0, stream,
                       part, e1, e2);
    hipLaunchKernelGGL(score_kernel,        dim3(512),  dim3(1024), 0, stream,
                       e1, e2, vc, P);
    hipLaunchKernelGGL(pax_kernel,          dim3(256),  dim3(256), 0, stream,
                       P, x, outp);
}